// Round 3
// baseline (15011.499 us; speedup 1.0000x reference)
//
#include <hip/hip_runtime.h>
#include <hip/hip_bf16.h>
#include <math.h>

#define B_SZ   8192
#define S_SZ   16
#define D_SZ   128
#define HID_SZ 1024
#define NUMF_SZ 103
#define GCN_SZ 40

__device__ __forceinline__ float f4c(const float4& v, int i) {
    return i == 0 ? v.x : i == 1 ? v.y : i == 2 ? v.z : v.w;
}

// Layer norm over rows of a [16][128] LDS tile. 256 threads: 16 rows x 16 lanes.
// Caller must __syncthreads() before and after.
__device__ __forceinline__ void layer_norm_tile(float (*M)[D_SZ],
                                                const float* __restrict__ g,
                                                const float* __restrict__ b,
                                                int t) {
    int r = t >> 4, c = t & 15;
    float s = 0.f;
#pragma unroll
    for (int i = 0; i < 8; ++i) s += M[r][c + 16 * i];
#pragma unroll
    for (int o = 8; o; o >>= 1) s += __shfl_xor(s, o, 16);
    float mean = s * (1.0f / 128.0f);
    float v = 0.f;
#pragma unroll
    for (int i = 0; i < 8; ++i) { float d = M[r][c + 16 * i] - mean; v += d * d; }
#pragma unroll
    for (int o = 8; o; o >>= 1) v += __shfl_xor(v, o, 16);
    float inv = rsqrtf(v * (1.0f / 128.0f) + 1e-5f);
#pragma unroll
    for (int i = 0; i < 8; ++i) {
        int cc = c + 16 * i;
        M[r][cc] = (M[r][cc] - mean) * inv * g[cc] + b[cc];
    }
}

// One workgroup per batch element b. Runs both encoder layers entirely in LDS,
// then computes acc1[b] = dot(flat, Wf[0:2048]) + dot(gcn, Wf[2048:2088]).
__global__ __launch_bounds__(256) void encoder_fused(
    const float* __restrict__ x, const float* __restrict__ gcn,
    const float* __restrict__ Wq, const float* __restrict__ bq,
    const float* __restrict__ Wk, const float* __restrict__ bk,
    const float* __restrict__ Wv, const float* __restrict__ bv,
    const float* __restrict__ Wo, const float* __restrict__ bo,
    const float* __restrict__ ln1g, const float* __restrict__ ln1b,
    const float* __restrict__ W1, const float* __restrict__ b1,
    const float* __restrict__ W2, const float* __restrict__ b2p,
    const float* __restrict__ ln2g, const float* __restrict__ ln2b,
    const float* __restrict__ Wf,
    float* __restrict__ acc1)
{
    __shared__ float A[S_SZ][D_SZ];   // current activations
    __shared__ float Qs[S_SZ][D_SZ];  // q proj, later ctx
    __shared__ float Ks[S_SZ][D_SZ];
    __shared__ float Vs[S_SZ][D_SZ];
    __shared__ float Hs[S_SZ][D_SZ];  // post-LN1 h
    __shared__ float F1[S_SZ][D_SZ];  // ff1 chunk; aliased as scores SC[8][16][16]
    __shared__ float redbuf[4];
    float (*SC)[16][16] = (float(*)[16][16])F1;

    const int b = blockIdx.x;
    const int t = threadIdx.x;
    const int j = t & 127;
    const int sg = t >> 7;      // 0 or 1
    const int s0 = sg * 8;      // rows s0..s0+7 owned by this thread

    // ---- load x[b] + positional encoding ----
#pragma unroll
    for (int i = 0; i < 8; ++i) {
        int idx = t + i * 256;
        int s = idx >> 7, c = idx & 127;
        float expo = (float)((c >> 1) * 2) * (1.0f / 128.0f);
        float denom = powf(10000.0f, expo);
        float ang = (float)s / denom;
        float pe = (c & 1) ? cosf(ang) : sinf(ang);
        A[s][c] = x[(size_t)b * (S_SZ * D_SZ) + idx] + pe;
    }
    __syncthreads();

    for (int l = 0; l < 2; ++l) {
        const float* wq = Wq + l * D_SZ * D_SZ;
        const float* wk = Wk + l * D_SZ * D_SZ;
        const float* wv = Wv + l * D_SZ * D_SZ;
        const float* wo = Wo + l * D_SZ * D_SZ;
        const float* w1 = W1 + l * D_SZ * HID_SZ;
        const float* w2 = W2 + l * HID_SZ * D_SZ;

        // ---- QKV projection: thread owns column j, rows s0..s0+7 ----
        float aq[8], ak[8], av[8];
        {
            float bqv = bq[l * 128 + j];
            float bkv = bk[l * 128 + j];
            float bvv = bv[l * 128 + j];
#pragma unroll
            for (int r = 0; r < 8; ++r) { aq[r] = bqv; ak[r] = bkv; av[r] = bvv; }
        }
        for (int k4 = 0; k4 < 32; ++k4) {
            float4 a[8];
#pragma unroll
            for (int r = 0; r < 8; ++r) a[r] = *(const float4*)&A[s0 + r][k4 * 4];
#pragma unroll
            for (int kk = 0; kk < 4; ++kk) {
                int k = k4 * 4 + kk;
                float wqv = wq[k * 128 + j];
                float wkv = wk[k * 128 + j];
                float wvv = wv[k * 128 + j];
#pragma unroll
                for (int r = 0; r < 8; ++r) {
                    float xv = f4c(a[r], kk);
                    aq[r] = fmaf(xv, wqv, aq[r]);
                    ak[r] = fmaf(xv, wkv, ak[r]);
                    av[r] = fmaf(xv, wvv, av[r]);
                }
            }
        }
#pragma unroll
        for (int r = 0; r < 8; ++r) {
            Qs[s0 + r][j] = aq[r];
            Ks[s0 + r][j] = ak[r];
            Vs[s0 + r][j] = av[r];
        }
        __syncthreads();

        // ---- attention scores (faithful raw-reshape grouping) ----
        // group g = s>>1; seq axis u = (s&1)*8 + (d>>4); e = d&15
        {
            int g = t >> 5;           // 0..7
            int u = (t >> 1) & 15;    // 0..15
            int tp0 = (t & 1) * 8;    // this thread does t' = tp0..tp0+7
            int qsr = 2 * g + (u >> 3), qc = (u & 7) * 16;
            float qrow[16];
#pragma unroll
            for (int e = 0; e < 16; ++e) qrow[e] = Qs[qsr][qc + e];
#pragma unroll
            for (int tt = 0; tt < 8; ++tt) {
                int tp = tp0 + tt;
                int ksr = 2 * g + (tp >> 3), kc = (tp & 7) * 16;
                float sacc = 0.f;
#pragma unroll
                for (int e = 0; e < 16; ++e) sacc = fmaf(qrow[e], Ks[ksr][kc + e], sacc);
                SC[g][u][tp] = sacc * 0.25f;  // scale = DH^-0.5
            }
        }
        __syncthreads();

        // ---- softmax over t' (16) ----
        if (t < 128) {
            int g = t >> 4, u = t & 15;
            float row[16];
            float mx = -1e30f;
#pragma unroll
            for (int tp = 0; tp < 16; ++tp) { row[tp] = SC[g][u][tp]; mx = fmaxf(mx, row[tp]); }
            float sum = 0.f;
#pragma unroll
            for (int tp = 0; tp < 16; ++tp) { row[tp] = __expf(row[tp] - mx); sum += row[tp]; }
            float inv = 1.0f / sum;
#pragma unroll
            for (int tp = 0; tp < 16; ++tp) SC[g][u][tp] = row[tp] * inv;
        }
        __syncthreads();

        // ---- ctx = P @ V, written into Qs (Qs reads all completed) ----
        float ctxv[8];
#pragma unroll
        for (int r = 0; r < 8; ++r) {
            int s = s0 + r;
            int g = s >> 1;
            int u = (s & 1) * 8 + (j >> 4);
            int e = j & 15;
            float c_ = 0.f;
#pragma unroll
            for (int tp = 0; tp < 16; ++tp)
                c_ = fmaf(SC[g][u][tp], Vs[2 * g + (tp >> 3)][(tp & 7) * 16 + e], c_);
            ctxv[r] = c_;
        }
#pragma unroll
        for (int r = 0; r < 8; ++r) Qs[s0 + r][j] = ctxv[r];
        __syncthreads();

        // ---- O projection + residual -> Hs; LN1 ----
        float ho[8];
        {
            float bov = bo[l * 128 + j];
#pragma unroll
            for (int r = 0; r < 8; ++r) ho[r] = bov;
        }
        for (int k4 = 0; k4 < 32; ++k4) {
            float4 a[8];
#pragma unroll
            for (int r = 0; r < 8; ++r) a[r] = *(const float4*)&Qs[s0 + r][k4 * 4];
#pragma unroll
            for (int kk = 0; kk < 4; ++kk) {
                float wov = wo[(k4 * 4 + kk) * 128 + j];
#pragma unroll
                for (int r = 0; r < 8; ++r) ho[r] = fmaf(f4c(a[r], kk), wov, ho[r]);
            }
        }
#pragma unroll
        for (int r = 0; r < 8; ++r) Hs[s0 + r][j] = ho[r] + A[s0 + r][j];
        __syncthreads();
        layer_norm_tile(Hs, ln1g + l * 128, ln1b + l * 128, t);
        __syncthreads();

        // ---- FF: 8 chunks of 128 hidden units; ff1 chunk in LDS ----
        float f2[8];
        {
            float b2v = b2p[l * 128 + j];
#pragma unroll
            for (int r = 0; r < 8; ++r) f2[r] = b2v;
        }
        for (int ch = 0; ch < 8; ++ch) {
            int m0 = ch * 128;
            float f1[8];
            {
                float b1v = b1[l * HID_SZ + m0 + j];
#pragma unroll
                for (int r = 0; r < 8; ++r) f1[r] = b1v;
            }
            for (int k4 = 0; k4 < 32; ++k4) {
                float4 a[8];
#pragma unroll
                for (int r = 0; r < 8; ++r) a[r] = *(const float4*)&Hs[s0 + r][k4 * 4];
#pragma unroll
                for (int kk = 0; kk < 4; ++kk) {
                    float w1v = w1[(k4 * 4 + kk) * HID_SZ + m0 + j];
#pragma unroll
                    for (int r = 0; r < 8; ++r) f1[r] = fmaf(f4c(a[r], kk), w1v, f1[r]);
                }
            }
#pragma unroll
            for (int r = 0; r < 8; ++r) F1[s0 + r][j] = fmaxf(f1[r], 0.f);
            __syncthreads();
            for (int m4 = 0; m4 < 32; ++m4) {
                float4 a[8];
#pragma unroll
                for (int r = 0; r < 8; ++r) a[r] = *(const float4*)&F1[s0 + r][m4 * 4];
#pragma unroll
                for (int mm = 0; mm < 4; ++mm) {
                    float w2v = w2[(m0 + m4 * 4 + mm) * 128 + j];
#pragma unroll
                    for (int r = 0; r < 8; ++r) f2[r] = fmaf(f4c(a[r], mm), w2v, f2[r]);
                }
            }
            __syncthreads();
        }
#pragma unroll
        for (int r = 0; r < 8; ++r) A[s0 + r][j] = f2[r] + Hs[s0 + r][j];
        __syncthreads();
        layer_norm_tile(A, ln2g + l * 128, ln2b + l * 128, t);
        __syncthreads();
    }

    // ---- partial head dot: flat part + gcn part ----
    float part = 0.f;
#pragma unroll
    for (int r = 0; r < 8; ++r) {
        int s = s0 + r;
        part = fmaf(A[s][j], Wf[s * 128 + j], part);
    }
    if (t < GCN_SZ)
        part = fmaf(gcn[(size_t)b * GCN_SZ + t], Wf[2048 + t], part);
#pragma unroll
    for (int o = 32; o; o >>= 1) part += __shfl_down(part, o);
    if ((t & 63) == 0) redbuf[t >> 6] = part;
    __syncthreads();
    if (t == 0) acc1[b] = redbuf[0] + redbuf[1] + redbuf[2] + redbuf[3];
}

// BN batch statistics: per-column sum / sumsq of n = num @ Wn + bnum.
// No n buffer stored (workspace kept tiny); n is recomputed in final_kernel.
__global__ __launch_bounds__(256) void num_stats_kernel(
    const float* __restrict__ num, const float* __restrict__ Wn,
    const float* __restrict__ bnum,
    float* __restrict__ ssum, float* __restrict__ ssq)
{
    __shared__ float NUM[16][NUMF_SZ + 1];
    __shared__ float cred[4][128];
    const int t = threadIdx.x;
    const int b0 = blockIdx.x * 16;
    const int j = t & 127, sg = t >> 7, s0 = sg * 8;

    for (int idx = t; idx < 16 * NUMF_SZ; idx += 256) {
        int r = idx / NUMF_SZ, f = idx - r * NUMF_SZ;
        NUM[r][f] = num[(size_t)(b0 + r) * NUMF_SZ + f];
    }
    __syncthreads();

    float acc[8];
    float bnv = bnum[j];
#pragma unroll
    for (int r = 0; r < 8; ++r) acc[r] = bnv;
    for (int f = 0; f < NUMF_SZ; ++f) {
        float w = Wn[f * 128 + j];
#pragma unroll
        for (int r = 0; r < 8; ++r) acc[r] = fmaf(NUM[s0 + r][f], w, acc[r]);
    }
    float lsum = 0.f, lsq = 0.f;
#pragma unroll
    for (int r = 0; r < 8; ++r) {
        lsum += acc[r];
        lsq = fmaf(acc[r], acc[r], lsq);
    }
    cred[sg][j] = lsum;
    cred[2 + sg][j] = lsq;
    __syncthreads();
    if (sg == 0) atomicAdd(&ssum[j], cred[0][j] + cred[1][j]);
    else         atomicAdd(&ssq[j],  cred[2][j] + cred[3][j]);
}

// Recompute n[b], BN(train-mode, biased var), final dot + sigmoid.
__global__ __launch_bounds__(128) void final_kernel(
    const float* __restrict__ num, const float* __restrict__ Wn,
    const float* __restrict__ bnum,
    const float* __restrict__ ssum, const float* __restrict__ ssq,
    const float* __restrict__ gamma, const float* __restrict__ beta,
    const float* __restrict__ Wf, const float* __restrict__ bfin,
    const float* __restrict__ acc1, float* __restrict__ out)
{
    const int b = blockIdx.x, jj = threadIdx.x;
    __shared__ float red2[2];
    __shared__ float NUMr[NUMF_SZ];
    if (jj < NUMF_SZ) NUMr[jj] = num[(size_t)b * NUMF_SZ + jj];
    __syncthreads();

    float nv = bnum[jj];
    for (int f = 0; f < NUMF_SZ; ++f)
        nv = fmaf(NUMr[f], Wn[f * 128 + jj], nv);

    float mean = ssum[jj] * (1.0f / (float)B_SZ);
    float var = ssq[jj] * (1.0f / (float)B_SZ) - mean * mean;
    float bnv = (nv - mean) * rsqrtf(var + 1e-5f) * gamma[jj] + beta[jj];
    float v = bnv * Wf[2088 + jj];
#pragma unroll
    for (int o = 32; o; o >>= 1) v += __shfl_down(v, o);
    if ((jj & 63) == 0) red2[jj >> 6] = v;
    __syncthreads();
    if (jj == 0) {
        float z = acc1[b] + red2[0] + red2[1] + bfin[0];
        out[b] = 1.0f / (1.0f + __expf(-z));
    }
}

extern "C" void kernel_launch(void* const* d_in, const int* in_sizes, int n_in,
                              void* d_out, int out_size, void* d_ws, size_t ws_size,
                              hipStream_t stream)
{
    const float* x    = (const float*)d_in[0];
    const float* gcn  = (const float*)d_in[1];
    const float* num  = (const float*)d_in[2];
    const float* Wq   = (const float*)d_in[3];
    const float* bq   = (const float*)d_in[4];
    const float* Wk   = (const float*)d_in[5];
    const float* bk   = (const float*)d_in[6];
    const float* Wv   = (const float*)d_in[7];
    const float* bv   = (const float*)d_in[8];
    const float* Wo   = (const float*)d_in[9];
    const float* bo   = (const float*)d_in[10];
    const float* ln1g = (const float*)d_in[11];
    const float* ln1b = (const float*)d_in[12];
    const float* W1   = (const float*)d_in[13];
    const float* b1   = (const float*)d_in[14];
    const float* W2   = (const float*)d_in[15];
    const float* b2p  = (const float*)d_in[16];
    const float* ln2g = (const float*)d_in[17];
    const float* ln2b = (const float*)d_in[18];
    const float* Wn   = (const float*)d_in[19];
    const float* bnum = (const float*)d_in[20];
    const float* bng  = (const float*)d_in[21];
    const float* bnb  = (const float*)d_in[22];
    const float* Wf   = (const float*)d_in[23];
    const float* bfin = (const float*)d_in[24];

    // Tiny workspace footprint: acc1 (8192 f32) + ssum/ssq (256 f32) = 33 KB.
    float* acc1 = (float*)d_ws;
    float* ssum = acc1 + B_SZ;
    float* ssq  = ssum + 128;
    hipMemsetAsync(ssum, 0, 2 * 128 * sizeof(float), stream);

    encoder_fused<<<B_SZ, 256, 0, stream>>>(x, gcn, Wq, bq, Wk, bk, Wv, bv, Wo, bo,
        ln1g, ln1b, W1, b1, W2, b2p, ln2g, ln2b, Wf, acc1);
    num_stats_kernel<<<B_SZ / 16, 256, 0, stream>>>(num, Wn, bnum, ssum, ssq);
    final_kernel<<<B_SZ, 128, 0, stream>>>(num, Wn, bnum, ssum, ssq, bng, bnb,
        Wf, bfin, acc1, (float*)d_out);
}

// Round 4
// 1460.753 us; speedup vs baseline: 10.2765x; 10.2765x over previous
//
#include <hip/hip_runtime.h>
#include <hip/hip_bf16.h>
#include <math.h>

#define B_SZ   8192
#define S_SZ   16
#define D_SZ   128
#define HID_SZ 1024
#define NUMF_SZ 103
#define GCN_SZ 40

typedef short bh8 __attribute__((ext_vector_type(8)));   // 8 bf16 (4 VGPRs)
typedef float fx4 __attribute__((ext_vector_type(4)));   // MFMA accumulator

__device__ __forceinline__ fx4 mfma16(bh8 a, bh8 b, fx4 c) {
    return __builtin_amdgcn_mfma_f32_16x16x32_bf16(a, b, c, 0, 0, 0);
}

// fp32 -> bf16 bits, round-nearest-even
__device__ __forceinline__ unsigned short f2b(float f) {
    unsigned u = __float_as_uint(f);
    return (unsigned short)((u + 0x7fffu + ((u >> 16) & 1u)) >> 16);
}

// Layer norm over rows of a [16][128] LDS tile. 256 threads: 16 rows x 16 lanes.
// Caller must __syncthreads() before and after.
__device__ __forceinline__ void layer_norm_tile(float (*M)[D_SZ],
                                                const float* __restrict__ g,
                                                const float* __restrict__ b,
                                                int t) {
    int r = t >> 4, c = t & 15;
    float s = 0.f;
#pragma unroll
    for (int i = 0; i < 8; ++i) s += M[r][c + 16 * i];
#pragma unroll
    for (int o = 8; o; o >>= 1) s += __shfl_xor(s, o, 16);
    float mean = s * (1.0f / 128.0f);
    float v = 0.f;
#pragma unroll
    for (int i = 0; i < 8; ++i) { float d = M[r][c + 16 * i] - mean; v += d * d; }
#pragma unroll
    for (int o = 8; o; o >>= 1) v += __shfl_xor(v, o, 16);
    float inv = rsqrtf(v * (1.0f / 128.0f) + 1e-5f);
#pragma unroll
    for (int i = 0; i < 8; ++i) {
        int cc = c + 16 * i;
        M[r][cc] = (M[r][cc] - mean) * inv * g[cc] + b[cc];
    }
}

// Transpose+cast all weights to bf16 [N][K] layouts (MFMA B-operand friendly).
// Grid: 1024 x 256 threads = 262144 = max element count (W1t/W2t).
__global__ __launch_bounds__(256) void prep_weights(
    const float* __restrict__ Wq, const float* __restrict__ Wk,
    const float* __restrict__ Wv, const float* __restrict__ Wo,
    const float* __restrict__ W1, const float* __restrict__ W2,
    unsigned short* __restrict__ Wqt, unsigned short* __restrict__ Wkt,
    unsigned short* __restrict__ Wvt, unsigned short* __restrict__ Wot,
    unsigned short* __restrict__ W1t, unsigned short* __restrict__ W2t)
{
    int i = blockIdx.x * 256 + threadIdx.x;
    if (i < 2 * 128 * 128) {                    // QKVO: [l][k][n] -> [l][n][k]
        int l = i >> 14, n = (i >> 7) & 127, k = i & 127;
        int s = l * 16384 + k * 128 + n;
        Wqt[i] = f2b(Wq[s]); Wkt[i] = f2b(Wk[s]);
        Wvt[i] = f2b(Wv[s]); Wot[i] = f2b(Wo[s]);
    }
    if (i < 2 * 1024 * 128) {
        {   // W1t: [l][k=128][n=1024] -> [l][n][k]
            int l = i >> 17, r = i & 131071, n = r >> 7, k = r & 127;
            W1t[i] = f2b(W1[l * 131072 + k * 1024 + n]);
        }
        {   // W2t: [l][k=1024][n=128] -> [l][n][k]
            int l = i >> 17, r = i & 131071, n = r >> 10, k = r & 1023;
            W2t[i] = f2b(W2[l * 131072 + k * 128 + n]);
        }
    }
}

// One workgroup per batch element. GEMMs via MFMA (bf16 in, fp32 acc);
// attention scores / softmax / PV / LN / head remain the verified fp32 code.
__global__ __launch_bounds__(256) void encoder_fused(
    const float* __restrict__ x, const float* __restrict__ gcn,
    const float* __restrict__ bq, const float* __restrict__ bk,
    const float* __restrict__ bv, const float* __restrict__ bo,
    const float* __restrict__ ln1g, const float* __restrict__ ln1b,
    const float* __restrict__ b1, const float* __restrict__ b2p,
    const float* __restrict__ ln2g, const float* __restrict__ ln2b,
    const float* __restrict__ Wf,
    const unsigned short* __restrict__ Wqt, const unsigned short* __restrict__ Wkt,
    const unsigned short* __restrict__ Wvt, const unsigned short* __restrict__ Wot,
    const unsigned short* __restrict__ W1t, const unsigned short* __restrict__ W2t,
    float* __restrict__ acc1)
{
    __shared__ float A[S_SZ][D_SZ];    // activations (residual, LN target)
    __shared__ float Qs[S_SZ][D_SZ];   // q proj, later ctx
    __shared__ float Ks[S_SZ][D_SZ];   // k proj; F1b aliases this during FF
    __shared__ float Vs[S_SZ][D_SZ];
    __shared__ float Hs[S_SZ][D_SZ];   // post-LN1 h
    __shared__ float SC[8][16][16];    // attention scores
    __shared__ unsigned short Bb[16][136];  // bf16 copy of current GEMM input (pad 8)
    __shared__ float redbuf[4];
    unsigned short (*F1b)[136] = (unsigned short (*)[136])(&Ks[0][0]);  // ff1 chunk bf16

    const int b = blockIdx.x;
    const int t = threadIdx.x;
    const int lane = t & 63, wv = t >> 6;
    const int ln = lane & 15, q = lane >> 4;       // MFMA lane decomposition
    const int j = t & 127;
    const int sg = t >> 7;
    const int s0 = sg * 8;
    const int row16 = t >> 4, col8 = (t & 15) * 8; // Bb packing map

    // ---- load x[b] + positional encoding ----
#pragma unroll
    for (int i = 0; i < 8; ++i) {
        int idx = t + i * 256;
        int s = idx >> 7, c = idx & 127;
        float expo = (float)((c >> 1) * 2) * (1.0f / 128.0f);
        float denom = powf(10000.0f, expo);
        float ang = (float)s / denom;
        float pe = (c & 1) ? cosf(ang) : sinf(ang);
        A[s][c] = x[(size_t)b * (S_SZ * D_SZ) + idx] + pe;
    }
    __syncthreads();

    for (int l = 0; l < 2; ++l) {
        // ---- Bb = bf16(A) ----
        {
            bh8 pk;
#pragma unroll
            for (int e = 0; e < 8; ++e) pk[e] = (short)f2b(A[row16][col8 + e]);
            *(bh8*)&Bb[row16][col8] = pk;
        }
        __syncthreads();

        // ---- QKV via MFMA: wave wv owns coltiles {2wv, 2wv+1} ----
        {
            bh8 af[4];
#pragma unroll
            for (int ks = 0; ks < 4; ++ks)
                af[ks] = *(const bh8*)&Bb[ln][q * 8 + 32 * ks];
            const unsigned short* Wt3[3] = {Wqt + l * 16384, Wkt + l * 16384, Wvt + l * 16384};
            const float* bias3[3] = {bq + l * 128, bk + l * 128, bv + l * 128};
            float (*dst3[3])[D_SZ] = {Qs, Ks, Vs};
            for (int mtx = 0; mtx < 3; ++mtx) {
#pragma unroll
                for (int i = 0; i < 2; ++i) {
                    int n = (wv * 2 + i) * 16 + ln;
                    fx4 acc = {0.f, 0.f, 0.f, 0.f};
#pragma unroll
                    for (int ks = 0; ks < 4; ++ks) {
                        bh8 bf = *(const bh8*)(Wt3[mtx] + n * 128 + q * 8 + 32 * ks);
                        acc = mfma16(af[ks], bf, acc);
                    }
                    float bb = bias3[mtx][n];
#pragma unroll
                    for (int r2 = 0; r2 < 4; ++r2)
                        dst3[mtx][q * 4 + r2][n] = acc[r2] + bb;
                }
            }
        }
        __syncthreads();

        // ---- attention scores (verified raw-reshape grouping) ----
        {
            int g = t >> 5;
            int u = (t >> 1) & 15;
            int tp0 = (t & 1) * 8;
            int qsr = 2 * g + (u >> 3), qc = (u & 7) * 16;
            float qrow[16];
#pragma unroll
            for (int e = 0; e < 16; ++e) qrow[e] = Qs[qsr][qc + e];
#pragma unroll
            for (int tt = 0; tt < 8; ++tt) {
                int tp = tp0 + tt;
                int ksr = 2 * g + (tp >> 3), kc = (tp & 7) * 16;
                float sacc = 0.f;
#pragma unroll
                for (int e = 0; e < 16; ++e) sacc = fmaf(qrow[e], Ks[ksr][kc + e], sacc);
                SC[g][u][tp] = sacc * 0.25f;
            }
        }
        __syncthreads();

        // ---- softmax over t' ----
        if (t < 128) {
            int g = t >> 4, u = t & 15;
            float row[16];
            float mx = -1e30f;
#pragma unroll
            for (int tp = 0; tp < 16; ++tp) { row[tp] = SC[g][u][tp]; mx = fmaxf(mx, row[tp]); }
            float sum = 0.f;
#pragma unroll
            for (int tp = 0; tp < 16; ++tp) { row[tp] = __expf(row[tp] - mx); sum += row[tp]; }
            float inv = 1.0f / sum;
#pragma unroll
            for (int tp = 0; tp < 16; ++tp) SC[g][u][tp] = row[tp] * inv;
        }
        __syncthreads();

        // ---- ctx = P @ V -> Qs (verified) ----
        {
            float ctxv[8];
#pragma unroll
            for (int r = 0; r < 8; ++r) {
                int s = s0 + r;
                int g = s >> 1;
                int u = (s & 1) * 8 + (j >> 4);
                int e = j & 15;
                float c_ = 0.f;
#pragma unroll
                for (int tp = 0; tp < 16; ++tp)
                    c_ = fmaf(SC[g][u][tp], Vs[2 * g + (tp >> 3)][(tp & 7) * 16 + e], c_);
                ctxv[r] = c_;
            }
#pragma unroll
            for (int r = 0; r < 8; ++r) Qs[s0 + r][j] = ctxv[r];
        }
        __syncthreads();

        // ---- Bb = bf16(ctx) ----
        {
            bh8 pk;
#pragma unroll
            for (int e = 0; e < 8; ++e) pk[e] = (short)f2b(Qs[row16][col8 + e]);
            *(bh8*)&Bb[row16][col8] = pk;
        }
        __syncthreads();

        // ---- O projection via MFMA + residual -> Hs ----
        {
            bh8 of[4];
#pragma unroll
            for (int ks = 0; ks < 4; ++ks)
                of[ks] = *(const bh8*)&Bb[ln][q * 8 + 32 * ks];
#pragma unroll
            for (int i = 0; i < 2; ++i) {
                int n = (wv * 2 + i) * 16 + ln;
                fx4 acc = {0.f, 0.f, 0.f, 0.f};
#pragma unroll
                for (int ks = 0; ks < 4; ++ks) {
                    bh8 bf = *(const bh8*)(Wot + l * 16384 + n * 128 + q * 8 + 32 * ks);
                    acc = mfma16(of[ks], bf, acc);
                }
                float bb = bo[l * 128 + n];
#pragma unroll
                for (int r2 = 0; r2 < 4; ++r2) {
                    int rr = q * 4 + r2;
                    Hs[rr][n] = acc[r2] + bb + A[rr][n];
                }
            }
        }
        __syncthreads();
        layer_norm_tile(Hs, ln1g + l * 128, ln1b + l * 128, t);
        __syncthreads();

        // ---- Bb = bf16(Hs) ----
        {
            bh8 pk;
#pragma unroll
            for (int e = 0; e < 8; ++e) pk[e] = (short)f2b(Hs[row16][col8 + e]);
            *(bh8*)&Bb[row16][col8] = pk;
        }
        __syncthreads();

        // ---- FF via MFMA: hid in 8 chunks of 128; F1 chunk kept bf16 in LDS ----
        {
            bh8 hf[4];
#pragma unroll
            for (int ks = 0; ks < 4; ++ks)
                hf[ks] = *(const bh8*)&Bb[ln][q * 8 + 32 * ks];
            fx4 f2a[2] = {{0.f, 0.f, 0.f, 0.f}, {0.f, 0.f, 0.f, 0.f}};
            for (int ch = 0; ch < 8; ++ch) {
                // FF1 chunk: relu(Hs @ W1[:, ch*128:+128] + b1) -> F1b (bf16)
#pragma unroll
                for (int i = 0; i < 2; ++i) {
                    int nloc = (wv * 2 + i) * 16 + ln;
                    int ng = ch * 128 + nloc;
                    fx4 acc = {0.f, 0.f, 0.f, 0.f};
#pragma unroll
                    for (int ks = 0; ks < 4; ++ks) {
                        bh8 bf = *(const bh8*)(W1t + l * 131072 + ng * 128 + q * 8 + 32 * ks);
                        acc = mfma16(hf[ks], bf, acc);
                    }
                    float bb = b1[l * HID_SZ + ng];
#pragma unroll
                    for (int r2 = 0; r2 < 4; ++r2) {
                        float v = acc[r2] + bb;
                        F1b[q * 4 + r2][nloc] = f2b(v > 0.f ? v : 0.f);
                    }
                }
                __syncthreads();
                // FF2 partial: f2a += F1chunk @ W2[ch*128:+128, :]
                bh8 ff[4];
#pragma unroll
                for (int ks = 0; ks < 4; ++ks)
                    ff[ks] = *(const bh8*)&F1b[ln][q * 8 + 32 * ks];
#pragma unroll
                for (int i = 0; i < 2; ++i) {
                    int n = (wv * 2 + i) * 16 + ln;
#pragma unroll
                    for (int ks = 0; ks < 4; ++ks) {
                        bh8 bf = *(const bh8*)(W2t + l * 131072 + n * 1024 + ch * 128 + q * 8 + 32 * ks);
                        f2a[i] = mfma16(ff[ks], bf, f2a[i]);
                    }
                }
                __syncthreads();
            }
            // epilogue: A = f2 + b2 + Hs (pre-LN2)
#pragma unroll
            for (int i = 0; i < 2; ++i) {
                int n = (wv * 2 + i) * 16 + ln;
                float bb = b2p[l * 128 + n];
#pragma unroll
                for (int r2 = 0; r2 < 4; ++r2) {
                    int rr = q * 4 + r2;
                    A[rr][n] = f2a[i][r2] + bb + Hs[rr][n];
                }
            }
        }
        __syncthreads();
        layer_norm_tile(A, ln2g + l * 128, ln2b + l * 128, t);
        __syncthreads();
    }

    // ---- partial head dot: flat part + gcn part (verified) ----
    float part = 0.f;
#pragma unroll
    for (int r = 0; r < 8; ++r) {
        int s = s0 + r;
        part = fmaf(A[s][j], Wf[s * 128 + j], part);
    }
    if (t < GCN_SZ)
        part = fmaf(gcn[(size_t)b * GCN_SZ + t], Wf[2048 + t], part);
#pragma unroll
    for (int o = 32; o; o >>= 1) part += __shfl_down(part, o);
    if ((t & 63) == 0) redbuf[t >> 6] = part;
    __syncthreads();
    if (t == 0) acc1[b] = redbuf[0] + redbuf[1] + redbuf[2] + redbuf[3];
}

// BN batch statistics: per-column sum / sumsq of n = num @ Wn + bnum.
__global__ __launch_bounds__(256) void num_stats_kernel(
    const float* __restrict__ num, const float* __restrict__ Wn,
    const float* __restrict__ bnum,
    float* __restrict__ ssum, float* __restrict__ ssq)
{
    __shared__ float NUM[16][NUMF_SZ + 1];
    __shared__ float cred[4][128];
    const int t = threadIdx.x;
    const int b0 = blockIdx.x * 16;
    const int j = t & 127, sg = t >> 7, s0 = sg * 8;

    for (int idx = t; idx < 16 * NUMF_SZ; idx += 256) {
        int r = idx / NUMF_SZ, f = idx - r * NUMF_SZ;
        NUM[r][f] = num[(size_t)(b0 + r) * NUMF_SZ + f];
    }
    __syncthreads();

    float acc[8];
    float bnv = bnum[j];
#pragma unroll
    for (int r = 0; r < 8; ++r) acc[r] = bnv;
    for (int f = 0; f < NUMF_SZ; ++f) {
        float w = Wn[f * 128 + j];
#pragma unroll
        for (int r = 0; r < 8; ++r) acc[r] = fmaf(NUM[s0 + r][f], w, acc[r]);
    }
    float lsum = 0.f, lsq = 0.f;
#pragma unroll
    for (int r = 0; r < 8; ++r) {
        lsum += acc[r];
        lsq = fmaf(acc[r], acc[r], lsq);
    }
    cred[sg][j] = lsum;
    cred[2 + sg][j] = lsq;
    __syncthreads();
    if (sg == 0) atomicAdd(&ssum[j], cred[0][j] + cred[1][j]);
    else         atomicAdd(&ssq[j],  cred[2][j] + cred[3][j]);
}

// Recompute n[b], BN(train-mode, biased var), final dot + sigmoid.
__global__ __launch_bounds__(128) void final_kernel(
    const float* __restrict__ num, const float* __restrict__ Wn,
    const float* __restrict__ bnum,
    const float* __restrict__ ssum, const float* __restrict__ ssq,
    const float* __restrict__ gamma, const float* __restrict__ beta,
    const float* __restrict__ Wf, const float* __restrict__ bfin,
    const float* __restrict__ acc1, float* __restrict__ out)
{
    const int b = blockIdx.x, jj = threadIdx.x;
    __shared__ float red2[2];
    __shared__ float NUMr[NUMF_SZ];
    if (jj < NUMF_SZ) NUMr[jj] = num[(size_t)b * NUMF_SZ + jj];
    __syncthreads();

    float nv = bnum[jj];
    for (int f = 0; f < NUMF_SZ; ++f)
        nv = fmaf(NUMr[f], Wn[f * 128 + jj], nv);

    float mean = ssum[jj] * (1.0f / (float)B_SZ);
    float var = ssq[jj] * (1.0f / (float)B_SZ) - mean * mean;
    float bnv = (nv - mean) * rsqrtf(var + 1e-5f) * gamma[jj] + beta[jj];
    float v = bnv * Wf[2088 + jj];
#pragma unroll
    for (int o = 32; o; o >>= 1) v += __shfl_down(v, o);
    if ((jj & 63) == 0) red2[jj >> 6] = v;
    __syncthreads();
    if (jj == 0) {
        float z = acc1[b] + red2[0] + red2[1] + bfin[0];
        out[b] = 1.0f / (1.0f + __expf(-z));
    }
}

extern "C" void kernel_launch(void* const* d_in, const int* in_sizes, int n_in,
                              void* d_out, int out_size, void* d_ws, size_t ws_size,
                              hipStream_t stream)
{
    const float* x    = (const float*)d_in[0];
    const float* gcn  = (const float*)d_in[1];
    const float* num  = (const float*)d_in[2];
    const float* Wq   = (const float*)d_in[3];
    const float* bq   = (const float*)d_in[4];
    const float* Wk   = (const float*)d_in[5];
    const float* bk   = (const float*)d_in[6];
    const float* Wv   = (const float*)d_in[7];
    const float* bv   = (const float*)d_in[8];
    const float* Wo   = (const float*)d_in[9];
    const float* bo   = (const float*)d_in[10];
    const float* ln1g = (const float*)d_in[11];
    const float* ln1b = (const float*)d_in[12];
    const float* W1   = (const float*)d_in[13];
    const float* b1   = (const float*)d_in[14];
    const float* W2   = (const float*)d_in[15];
    const float* b2p  = (const float*)d_in[16];
    const float* ln2g = (const float*)d_in[17];
    const float* ln2b = (const float*)d_in[18];
    const float* Wn   = (const float*)d_in[19];
    const float* bnum = (const float*)d_in[20];
    const float* bng  = (const float*)d_in[21];
    const float* bnb  = (const float*)d_in[22];
    const float* Wf   = (const float*)d_in[23];
    const float* bfin = (const float*)d_in[24];

    // ws layout: acc1 (8192 f32) | ssum (128) | ssq (128) | pad | bf16 weights (1.31 MB)
    float* acc1 = (float*)d_ws;
    float* ssum = acc1 + B_SZ;
    float* ssq  = ssum + 128;
    unsigned short* wb = (unsigned short*)((char*)d_ws + 40960);
    unsigned short* Wqt = wb;
    unsigned short* Wkt = wb + 32768;
    unsigned short* Wvt = wb + 65536;
    unsigned short* Wot = wb + 98304;
    unsigned short* W1t = wb + 131072;
    unsigned short* W2t = wb + 393216;

    hipMemsetAsync(ssum, 0, 2 * 128 * sizeof(float), stream);
    prep_weights<<<1024, 256, 0, stream>>>(Wq, Wk, Wv, Wo, W1, W2,
        Wqt, Wkt, Wvt, Wot, W1t, W2t);
    encoder_fused<<<B_SZ, 256, 0, stream>>>(x, gcn, bq, bk, bv, bo,
        ln1g, ln1b, b1, b2p, ln2g, ln2b, Wf,
        Wqt, Wkt, Wvt, Wot, W1t, W2t, acc1);
    num_stats_kernel<<<B_SZ / 16, 256, 0, stream>>>(num, Wn, bnum, ssum, ssq);
    final_kernel<<<B_SZ, 128, 0, stream>>>(num, Wn, bnum, ssum, ssq, bng, bnb,
        Wf, bfin, acc1, (float*)d_out);
}

// Round 5
// 1403.666 us; speedup vs baseline: 10.6945x; 1.0407x over previous
//
#include <hip/hip_runtime.h>
#include <hip/hip_bf16.h>
#include <math.h>

#define B_SZ   8192
#define S_SZ   16
#define D_SZ   128
#define HID_SZ 1024
#define NUMF_SZ 103
#define GCN_SZ 40
#define LDPAD  136

typedef short bh8 __attribute__((ext_vector_type(8)));   // 8 bf16 (4 VGPRs)
typedef float fx4 __attribute__((ext_vector_type(4)));   // MFMA accumulator

// Wave-level LDS fence: all DS ops of this wave complete; lockstep wave64 makes
// this sufficient for intra-wave cross-lane LDS communication (no __syncthreads).
#define WAVE_SYNC() __asm__ volatile("s_waitcnt lgkmcnt(0)" ::: "memory")

__device__ __forceinline__ fx4 mfma16(bh8 a, bh8 b, fx4 c) {
    return __builtin_amdgcn_mfma_f32_16x16x32_bf16(a, b, c, 0, 0, 0);
}

// fp32 -> bf16 bits, round-nearest-even
__device__ __forceinline__ unsigned short f2b(float f) {
    unsigned u = __float_as_uint(f);
    return (unsigned short)((u + 0x7fffu + ((u >> 16) & 1u)) >> 16);
}
__device__ __forceinline__ float bu2f(unsigned short u) {
    return __uint_as_float(((unsigned)u) << 16);
}

// In-register LayerNorm over C-layout tile rows. Lane (q,ln) holds rows q*4+r2
// at cols {ct*16+ln}. Row reduction = per-lane partial + 16-lane xor butterfly
// (stays within the quad's 16-lane group for masks < 16).
__device__ __forceinline__ void ln_rows(fx4* h, const float* __restrict__ g,
                                        const float* __restrict__ bt, int ln) {
    float mean[4], inv[4];
#pragma unroll
    for (int r2 = 0; r2 < 4; ++r2) {
        float s = 0.f;
#pragma unroll
        for (int ct = 0; ct < 8; ++ct) s += h[ct][r2];
#pragma unroll
        for (int m = 1; m < 16; m <<= 1) s += __shfl_xor(s, m);
        mean[r2] = s * (1.0f / 128.0f);
        float v = 0.f;
#pragma unroll
        for (int ct = 0; ct < 8; ++ct) { float d = h[ct][r2] - mean[r2]; v += d * d; }
#pragma unroll
        for (int m = 1; m < 16; m <<= 1) v += __shfl_xor(v, m);
        inv[r2] = rsqrtf(v * (1.0f / 128.0f) + 1e-5f);
    }
#pragma unroll
    for (int ct = 0; ct < 8; ++ct) {
        float gg = g[ct * 16 + ln], bb = bt[ct * 16 + ln];
#pragma unroll
        for (int r2 = 0; r2 < 4; ++r2)
            h[ct][r2] = (h[ct][r2] - mean[r2]) * inv[r2] * gg + bb;
    }
}

// Transpose+cast weights to bf16 [N][K] + fill PE table.
__global__ __launch_bounds__(256) void prep_weights(
    const float* __restrict__ Wq, const float* __restrict__ Wk,
    const float* __restrict__ Wv, const float* __restrict__ Wo,
    const float* __restrict__ W1, const float* __restrict__ W2,
    unsigned short* __restrict__ Wqt, unsigned short* __restrict__ Wkt,
    unsigned short* __restrict__ Wvt, unsigned short* __restrict__ Wot,
    unsigned short* __restrict__ W1t, unsigned short* __restrict__ W2t,
    float* __restrict__ PEt)
{
    int i = blockIdx.x * 256 + threadIdx.x;
    if (i < 2048) {  // PE table [16][128]
        int s = i >> 7, c = i & 127;
        float expo = (float)((c >> 1) * 2) * (1.0f / 128.0f);
        float denom = powf(10000.0f, expo);
        float ang = (float)s / denom;
        PEt[i] = (c & 1) ? cosf(ang) : sinf(ang);
    }
    if (i < 2 * 128 * 128) {                    // QKVO: [l][k][n] -> [l][n][k]
        int l = i >> 14, n = (i >> 7) & 127, k = i & 127;
        int s = l * 16384 + k * 128 + n;
        Wqt[i] = f2b(Wq[s]); Wkt[i] = f2b(Wk[s]);
        Wvt[i] = f2b(Wv[s]); Wot[i] = f2b(Wo[s]);
    }
    if (i < 2 * 1024 * 128) {
        {   // W1t: [l][k=128][n=1024] -> [l][n][k]
            int l = i >> 17, r = i & 131071, n = r >> 7, k = r & 127;
            W1t[i] = f2b(W1[l * 131072 + k * 1024 + n]);
        }
        {   // W2t: [l][k=1024][n=128] -> [l][n][k]
            int l = i >> 17, r = i & 131071, n = r >> 10, k = r & 1023;
            W2t[i] = f2b(W2[l * 131072 + k * 128 + n]);
        }
    }
}

// One WAVE per batch element; 4 waves/block, fully independent (no barriers).
// State in registers (C-layout fx4[8]); wave-private LDS for layout transforms.
__global__ __launch_bounds__(256) void encoder_fused(
    const float* __restrict__ x, const float* __restrict__ gcn,
    const float* __restrict__ bq, const float* __restrict__ bk,
    const float* __restrict__ bv, const float* __restrict__ bo,
    const float* __restrict__ ln1g, const float* __restrict__ ln1b,
    const float* __restrict__ b1, const float* __restrict__ b2p,
    const float* __restrict__ ln2g, const float* __restrict__ ln2b,
    const float* __restrict__ Wf,
    const unsigned short* __restrict__ Wqt, const unsigned short* __restrict__ Wkt,
    const unsigned short* __restrict__ Wvt, const unsigned short* __restrict__ Wot,
    const unsigned short* __restrict__ W1t, const unsigned short* __restrict__ W2t,
    const float* __restrict__ PEt,
    float* __restrict__ acc1)
{
    __shared__ unsigned short SM[4][3][16][LDPAD];   // 52.2 KB: per-wave Qb/Kb/Vb
    const int t = threadIdx.x;
    const int wv = t >> 6, lane = t & 63;
    const int q = lane >> 4, ln = lane & 15;         // MFMA lane decomposition
    const int b = blockIdx.x * 4 + wv;
    unsigned short (*Qb)[LDPAD] = SM[wv][0];
    unsigned short (*Kb)[LDPAD] = SM[wv][1];
    unsigned short (*Vb)[LDPAD] = SM[wv][2];

    // ---- load x[b] + PE into C-layout registers ----
    fx4 cur[8];
    const float* xb = x + (size_t)b * (S_SZ * D_SZ);
#pragma unroll
    for (int ct = 0; ct < 8; ++ct) {
#pragma unroll
        for (int r2 = 0; r2 < 4; ++r2) {
            int idx = (q * 4 + r2) * 128 + ct * 16 + ln;
            cur[ct][r2] = xb[idx] + PEt[idx];
        }
    }

    for (int l = 0; l < 2; ++l) {
        // ---- stage cur -> Qb (bf16), read A-fragments ----
#pragma unroll
        for (int ct = 0; ct < 8; ++ct)
#pragma unroll
            for (int r2 = 0; r2 < 4; ++r2)
                Qb[q * 4 + r2][ct * 16 + ln] = f2b(cur[ct][r2]);
        WAVE_SYNC();
        bh8 af[4];
#pragma unroll
        for (int ks = 0; ks < 4; ++ks) af[ks] = *(const bh8*)&Qb[ln][ks * 32 + q * 8];
        WAVE_SYNC();   // af reads landed before Qb is overwritten below

        // ---- QKV via MFMA -> Qb/Kb/Vb (bf16, C-layout writes) ----
        {
            const unsigned short* Wt3[3] = {Wqt + l * 16384, Wkt + l * 16384, Wvt + l * 16384};
            const float* b3[3] = {bq + l * 128, bk + l * 128, bv + l * 128};
#pragma unroll
            for (int mtx = 0; mtx < 3; ++mtx) {
                unsigned short (*dst)[LDPAD] = (mtx == 0) ? Qb : (mtx == 1) ? Kb : Vb;
                const unsigned short* W = Wt3[mtx];
                const float* bias = b3[mtx];
#pragma unroll
                for (int ct = 0; ct < 8; ++ct) {
                    int n = ct * 16 + ln;
                    fx4 acc = {0.f, 0.f, 0.f, 0.f};
#pragma unroll
                    for (int ks = 0; ks < 4; ++ks) {
                        bh8 bf = *(const bh8*)(W + n * 128 + ks * 32 + q * 8);
                        acc = mfma16(af[ks], bf, acc);
                    }
                    float bb = bias[n];
#pragma unroll
                    for (int r2 = 0; r2 < 4; ++r2)
                        dst[q * 4 + r2][n] = f2b(acc[r2] + bb);
                }
            }
        }
        WAVE_SYNC();

        // ---- attention: lane handles group g = lane>>3, rows u0, u0+1 ----
        {
            int g = lane >> 3, u0 = (lane & 7) * 2;
            float qr[2][16];
#pragma unroll
            for (int h = 0; h < 2; ++h) {
                int u = u0 + h;
                int qsr = 2 * g + (u >> 3), qc = (u & 7) * 16;
                bh8 a0 = *(const bh8*)&Qb[qsr][qc];
                bh8 a1 = *(const bh8*)&Qb[qsr][qc + 8];
#pragma unroll
                for (int e = 0; e < 8; ++e) {
                    qr[h][e] = bu2f((unsigned short)a0[e]);
                    qr[h][8 + e] = bu2f((unsigned short)a1[e]);
                }
            }
            float p[2][16];
#pragma unroll
            for (int tp = 0; tp < 16; ++tp) {
                int ksr = 2 * g + (tp >> 3), kc = (tp & 7) * 16;
                bh8 k0 = *(const bh8*)&Kb[ksr][kc];
                bh8 k1 = *(const bh8*)&Kb[ksr][kc + 8];
                float d0 = 0.f, d1 = 0.f;
#pragma unroll
                for (int e = 0; e < 8; ++e) {
                    float kv = bu2f((unsigned short)k0[e]);
                    d0 = fmaf(qr[0][e], kv, d0); d1 = fmaf(qr[1][e], kv, d1);
                }
#pragma unroll
                for (int e = 0; e < 8; ++e) {
                    float kv = bu2f((unsigned short)k1[e]);
                    d0 = fmaf(qr[0][8 + e], kv, d0); d1 = fmaf(qr[1][8 + e], kv, d1);
                }
                p[0][tp] = d0 * 0.25f; p[1][tp] = d1 * 0.25f;
            }
            // softmax (in-lane, rows of 16)
#pragma unroll
            for (int h = 0; h < 2; ++h) {
                float mx = -1e30f;
#pragma unroll
                for (int tp = 0; tp < 16; ++tp) mx = fmaxf(mx, p[h][tp]);
                float sum = 0.f;
#pragma unroll
                for (int tp = 0; tp < 16; ++tp) { p[h][tp] = __expf(p[h][tp] - mx); sum += p[h][tp]; }
                float is = 1.0f / sum;
#pragma unroll
                for (int tp = 0; tp < 16; ++tp) p[h][tp] *= is;
            }
            // ctx = P @ V
            float ctx[2][16];
#pragma unroll
            for (int h = 0; h < 2; ++h)
#pragma unroll
                for (int e = 0; e < 16; ++e) ctx[h][e] = 0.f;
#pragma unroll
            for (int tp = 0; tp < 16; ++tp) {
                int vsr = 2 * g + (tp >> 3), vc = (tp & 7) * 16;
                bh8 v0 = *(const bh8*)&Vb[vsr][vc];
                bh8 v1 = *(const bh8*)&Vb[vsr][vc + 8];
#pragma unroll
                for (int e = 0; e < 8; ++e) {
                    float vv = bu2f((unsigned short)v0[e]);
                    ctx[0][e] = fmaf(p[0][tp], vv, ctx[0][e]);
                    ctx[1][e] = fmaf(p[1][tp], vv, ctx[1][e]);
                }
#pragma unroll
                for (int e = 0; e < 8; ++e) {
                    float vv = bu2f((unsigned short)v1[e]);
                    ctx[0][8 + e] = fmaf(p[0][tp], vv, ctx[0][8 + e]);
                    ctx[1][8 + e] = fmaf(p[1][tp], vv, ctx[1][8 + e]);
                }
            }
            // write ctx -> Qb at (s = 2g+(u>>3), d = (u&7)*16 + e)
#pragma unroll
            for (int h = 0; h < 2; ++h) {
                int u = u0 + h;
                int s = 2 * g + (u >> 3), dc = (u & 7) * 16;
                bh8 c0, c1;
#pragma unroll
                for (int e = 0; e < 8; ++e) {
                    c0[e] = (short)f2b(ctx[h][e]);
                    c1[e] = (short)f2b(ctx[h][8 + e]);
                }
                *(bh8*)&Qb[s][dc] = c0;
                *(bh8*)&Qb[s][dc + 8] = c1;
            }
        }
        WAVE_SYNC();

        // ---- O projection + residual -> h8; LN1 (in-register) ----
        fx4 h8[8];
        {
            bh8 afc[4];
#pragma unroll
            for (int ks = 0; ks < 4; ++ks) afc[ks] = *(const bh8*)&Qb[ln][ks * 32 + q * 8];
#pragma unroll
            for (int ct = 0; ct < 8; ++ct) {
                int n = ct * 16 + ln;
                fx4 acc = {0.f, 0.f, 0.f, 0.f};
#pragma unroll
                for (int ks = 0; ks < 4; ++ks) {
                    bh8 bf = *(const bh8*)(Wot + l * 16384 + n * 128 + ks * 32 + q * 8);
                    acc = mfma16(afc[ks], bf, acc);
                }
                float bb = bo[l * 128 + n];
#pragma unroll
                for (int r2 = 0; r2 < 4; ++r2)
                    h8[ct][r2] = acc[r2] + bb + cur[ct][r2];
            }
        }
        ln_rows(h8, ln1g + l * 128, ln1b + l * 128, ln);

        // ---- stage h8 -> Kb, read FF A-fragments ----
#pragma unroll
        for (int ct = 0; ct < 8; ++ct)
#pragma unroll
            for (int r2 = 0; r2 < 4; ++r2)
                Kb[q * 4 + r2][ct * 16 + ln] = f2b(h8[ct][r2]);
        WAVE_SYNC();
        bh8 afh[4];
#pragma unroll
        for (int ks = 0; ks < 4; ++ks) afh[ks] = *(const bh8*)&Kb[ln][ks * 32 + q * 8];
        WAVE_SYNC();

        // ---- FF: 8 chunks of 128 hidden; F1 chunk staged bf16 in Vb ----
        fx4 f2a[8];
#pragma unroll
        for (int ct = 0; ct < 8; ++ct) f2a[ct] = fx4{0.f, 0.f, 0.f, 0.f};
        for (int ch = 0; ch < 8; ++ch) {
#pragma unroll
            for (int ct = 0; ct < 8; ++ct) {
                int n = ct * 16 + ln;
                fx4 acc = {0.f, 0.f, 0.f, 0.f};
#pragma unroll
                for (int ks = 0; ks < 4; ++ks) {
                    bh8 bf = *(const bh8*)(W1t + l * 131072 + (ch * 128 + n) * 128 + ks * 32 + q * 8);
                    acc = mfma16(afh[ks], bf, acc);
                }
                float bb = b1[l * HID_SZ + ch * 128 + n];
#pragma unroll
                for (int r2 = 0; r2 < 4; ++r2) {
                    float v2 = acc[r2] + bb;
                    Vb[q * 4 + r2][n] = f2b(v2 > 0.f ? v2 : 0.f);
                }
            }
            WAVE_SYNC();
            bh8 ff[4];
#pragma unroll
            for (int ks = 0; ks < 4; ++ks) ff[ks] = *(const bh8*)&Vb[ln][ks * 32 + q * 8];
            WAVE_SYNC();
#pragma unroll
            for (int ct = 0; ct < 8; ++ct) {
                int n = ct * 16 + ln;
#pragma unroll
                for (int ks = 0; ks < 4; ++ks) {
                    bh8 bf = *(const bh8*)(W2t + l * 131072 + n * 1024 + ch * 128 + ks * 32 + q * 8);
                    f2a[ct] = mfma16(ff[ks], bf, f2a[ct]);
                }
            }
        }
        // epilogue: cur = f2 + b2 + h8; LN2
#pragma unroll
        for (int ct = 0; ct < 8; ++ct) {
            float bb = b2p[l * 128 + ct * 16 + ln];
#pragma unroll
            for (int r2 = 0; r2 < 4; ++r2)
                cur[ct][r2] = f2a[ct][r2] + bb + h8[ct][r2];
        }
        ln_rows(cur, ln2g + l * 128, ln2b + l * 128, ln);
    }

    // ---- head partial: flat + gcn, full-wave butterfly ----
    float part = 0.f;
#pragma unroll
    for (int ct = 0; ct < 8; ++ct)
#pragma unroll
        for (int r2 = 0; r2 < 4; ++r2)
            part = fmaf(cur[ct][r2], Wf[(q * 4 + r2) * 128 + ct * 16 + ln], part);
    if (lane < GCN_SZ)
        part = fmaf(gcn[(size_t)b * GCN_SZ + lane], Wf[2048 + lane], part);
#pragma unroll
    for (int off = 32; off; off >>= 1) part += __shfl_xor(part, off);
    if (lane == 0) acc1[b] = part;
}

// BN batch statistics: per-column sum / sumsq of n = num @ Wn + bnum.
__global__ __launch_bounds__(256) void num_stats_kernel(
    const float* __restrict__ num, const float* __restrict__ Wn,
    const float* __restrict__ bnum,
    float* __restrict__ ssum, float* __restrict__ ssq)
{
    __shared__ float NUM[16][NUMF_SZ + 1];
    __shared__ float cred[4][128];
    const int t = threadIdx.x;
    const int b0 = blockIdx.x * 16;
    const int j = t & 127, sg = t >> 7, s0 = sg * 8;

    for (int idx = t; idx < 16 * NUMF_SZ; idx += 256) {
        int r = idx / NUMF_SZ, f = idx - r * NUMF_SZ;
        NUM[r][f] = num[(size_t)(b0 + r) * NUMF_SZ + f];
    }
    __syncthreads();

    float acc[8];
    float bnv = bnum[j];
#pragma unroll
    for (int r = 0; r < 8; ++r) acc[r] = bnv;
    for (int f = 0; f < NUMF_SZ; ++f) {
        float w = Wn[f * 128 + j];
#pragma unroll
        for (int r = 0; r < 8; ++r) acc[r] = fmaf(NUM[s0 + r][f], w, acc[r]);
    }
    float lsum = 0.f, lsq = 0.f;
#pragma unroll
    for (int r = 0; r < 8; ++r) {
        lsum += acc[r];
        lsq = fmaf(acc[r], acc[r], lsq);
    }
    cred[sg][j] = lsum;
    cred[2 + sg][j] = lsq;
    __syncthreads();
    if (sg == 0) atomicAdd(&ssum[j], cred[0][j] + cred[1][j]);
    else         atomicAdd(&ssq[j],  cred[2][j] + cred[3][j]);
}

// Recompute n[b], BN(train-mode, biased var), final dot + sigmoid.
__global__ __launch_bounds__(128) void final_kernel(
    const float* __restrict__ num, const float* __restrict__ Wn,
    const float* __restrict__ bnum,
    const float* __restrict__ ssum, const float* __restrict__ ssq,
    const float* __restrict__ gamma, const float* __restrict__ beta,
    const float* __restrict__ Wf, const float* __restrict__ bfin,
    const float* __restrict__ acc1, float* __restrict__ out)
{
    const int b = blockIdx.x, jj = threadIdx.x;
    __shared__ float red2[2];
    __shared__ float NUMr[NUMF_SZ];
    if (jj < NUMF_SZ) NUMr[jj] = num[(size_t)b * NUMF_SZ + jj];
    __syncthreads();

    float nv = bnum[jj];
    for (int f = 0; f < NUMF_SZ; ++f)
        nv = fmaf(NUMr[f], Wn[f * 128 + jj], nv);

    float mean = ssum[jj] * (1.0f / (float)B_SZ);
    float var = ssq[jj] * (1.0f / (float)B_SZ) - mean * mean;
    float bnv = (nv - mean) * rsqrtf(var + 1e-5f) * gamma[jj] + beta[jj];
    float v = bnv * Wf[2088 + jj];
#pragma unroll
    for (int o = 32; o; o >>= 1) v += __shfl_down(v, o);
    if ((jj & 63) == 0) red2[jj >> 6] = v;
    __syncthreads();
    if (jj == 0) {
        float z = acc1[b] + red2[0] + red2[1] + bfin[0];
        out[b] = 1.0f / (1.0f + __expf(-z));
    }
}

extern "C" void kernel_launch(void* const* d_in, const int* in_sizes, int n_in,
                              void* d_out, int out_size, void* d_ws, size_t ws_size,
                              hipStream_t stream)
{
    const float* x    = (const float*)d_in[0];
    const float* gcn  = (const float*)d_in[1];
    const float* num  = (const float*)d_in[2];
    const float* Wq   = (const float*)d_in[3];
    const float* bq   = (const float*)d_in[4];
    const float* Wk   = (const float*)d_in[5];
    const float* bk   = (const float*)d_in[6];
    const float* Wv   = (const float*)d_in[7];
    const float* bv   = (const float*)d_in[8];
    const float* Wo   = (const float*)d_in[9];
    const float* bo   = (const float*)d_in[10];
    const float* ln1g = (const float*)d_in[11];
    const float* ln1b = (const float*)d_in[12];
    const float* W1   = (const float*)d_in[13];
    const float* b1   = (const float*)d_in[14];
    const float* W2   = (const float*)d_in[15];
    const float* b2p  = (const float*)d_in[16];
    const float* ln2g = (const float*)d_in[17];
    const float* ln2b = (const float*)d_in[18];
    const float* Wn   = (const float*)d_in[19];
    const float* bnum = (const float*)d_in[20];
    const float* bng  = (const float*)d_in[21];
    const float* bnb  = (const float*)d_in[22];
    const float* Wf   = (const float*)d_in[23];
    const float* bfin = (const float*)d_in[24];

    // ws: acc1 (8192 f32) | ssum | ssq | pad to 40960 B | bf16 weights | PE table
    float* acc1 = (float*)d_ws;
    float* ssum = acc1 + B_SZ;
    float* ssq  = ssum + 128;
    unsigned short* wb = (unsigned short*)((char*)d_ws + 40960);
    unsigned short* Wqt = wb;
    unsigned short* Wkt = wb + 32768;
    unsigned short* Wvt = wb + 65536;
    unsigned short* Wot = wb + 98304;
    unsigned short* W1t = wb + 131072;
    unsigned short* W2t = wb + 393216;
    float* PEt = (float*)((char*)d_ws + 40960 + 1310720);

    hipMemsetAsync(ssum, 0, 2 * 128 * sizeof(float), stream);
    prep_weights<<<1024, 256, 0, stream>>>(Wq, Wk, Wv, Wo, W1, W2,
        Wqt, Wkt, Wvt, Wot, W1t, W2t, PEt);
    encoder_fused<<<B_SZ / 4, 256, 0, stream>>>(x, gcn, bq, bk, bv, bo,
        ln1g, ln1b, b1, b2p, ln2g, ln2b, Wf,
        Wqt, Wkt, Wvt, Wot, W1t, W2t, PEt, acc1);
    num_stats_kernel<<<B_SZ / 16, 256, 0, stream>>>(num, Wn, bnum, ssum, ssq);
    final_kernel<<<B_SZ, 128, 0, stream>>>(num, Wn, bnum, ssum, ssq, bng, bnb,
        Wf, bfin, acc1, (float*)d_out);
}

// Round 6
// 642.897 us; speedup vs baseline: 23.3498x; 2.1833x over previous
//
#include <hip/hip_runtime.h>
#include <hip/hip_bf16.h>
#include <math.h>

#define B_SZ   8192
#define S_SZ   16
#define D_SZ   128
#define HID_SZ 1024
#define NUMF_SZ 103
#define GCN_SZ 40
#define G_B    8                 // batch elements per block
#define NBLK   (B_SZ / G_B)      // 1024 blocks
#define STRD   136               // LDS row stride (shorts), pad 8

typedef short bh8 __attribute__((ext_vector_type(8)));   // 8 bf16 (4 VGPRs)
typedef float fx4 __attribute__((ext_vector_type(4)));   // MFMA accumulator

__device__ __forceinline__ fx4 mfma16(bh8 a, bh8 b, fx4 c) {
    return __builtin_amdgcn_mfma_f32_16x16x32_bf16(a, b, c, 0, 0, 0);
}

// fp32 -> bf16 bits, round-nearest-even
__device__ __forceinline__ unsigned short f2b(float f) {
    unsigned u = __float_as_uint(f);
    return (unsigned short)((u + 0x7fffu + ((u >> 16) & 1u)) >> 16);
}
__device__ __forceinline__ float bu2f(unsigned short u) {
    return __uint_as_float(((unsigned)u) << 16);
}

// Swizzle all weights into B-fragment-linear bf16 order:
//   QKVO : [l][nt(8)][ks(4)][lane(64)][e(8)]   (nt = n/16, k = ks*32 + q*8 + e)
//   W1   : [l][nt(64)][ks(4)][lane][e]
//   W2   : [l][nt(8)][kt(32)][lane][e]
// so a wave's fragment load is one contiguous 1KB block (lane*16B).
__global__ __launch_bounds__(256) void prep_weights(
    const float* __restrict__ Wq, const float* __restrict__ Wk,
    const float* __restrict__ Wv, const float* __restrict__ Wo,
    const float* __restrict__ W1, const float* __restrict__ W2,
    unsigned short* __restrict__ WswQ, unsigned short* __restrict__ WswK,
    unsigned short* __restrict__ WswV, unsigned short* __restrict__ WswO,
    unsigned short* __restrict__ Wsw1, unsigned short* __restrict__ Wsw2,
    float* __restrict__ PEt)
{
    int i = blockIdx.x * 256 + threadIdx.x;
    if (i < 2048) {  // PE table [16][128]
        int s = i >> 7, c = i & 127;
        float expo = (float)((c >> 1) * 2) * (1.0f / 128.0f);
        float denom = powf(10000.0f, expo);
        float ang = (float)s / denom;
        PEt[i] = (c & 1) ? cosf(ang) : sinf(ang);
    }
    if (i < 2 * 16384) {   // QKVO, dst-driven
        int l = i >> 14, r = i & 16383;
        int nt = r >> 11, ks = (r >> 9) & 3, lane = (r >> 3) & 63, e = r & 7;
        int k = ks * 32 + (lane >> 4) * 8 + e;
        int n = nt * 16 + (lane & 15);
        int s = l * 16384 + k * 128 + n;
        WswQ[i] = f2b(Wq[s]); WswK[i] = f2b(Wk[s]);
        WswV[i] = f2b(Wv[s]); WswO[i] = f2b(Wo[s]);
    }
    {   // W1: src [l][k=128][n=1024]
        int l = i >> 17, r = i & 131071;
        int nt = r >> 11, ks = (r >> 9) & 3, lane = (r >> 3) & 63, e = r & 7;
        int k = ks * 32 + (lane >> 4) * 8 + e;
        int n = nt * 16 + (lane & 15);
        Wsw1[i] = f2b(W1[l * 131072 + k * 1024 + n]);
    }
    {   // W2: src [l][k=1024][n=128]
        int l = i >> 17, r = i & 131071;
        int nt = r >> 14, kt = (r >> 9) & 31, lane = (r >> 3) & 63, e = r & 7;
        int k = kt * 32 + (lane >> 4) * 8 + e;
        int n = nt * 16 + (lane & 15);
        Wsw2[i] = f2b(W2[l * 131072 + k * 128 + n]);
    }
}

// Block = 4 waves = 8 batch elements (m-tile mt == batch element mt).
// Waves split N: wave w owns cols [w*32, w*32+32). Each B-frag load feeds
// 8 MFMAs (all m-tiles) -> 8:1 MFMA:load, 8x less weight traffic than R5.
__global__ __launch_bounds__(256) void encoder_fused(
    const float* __restrict__ x, const float* __restrict__ gcn,
    const float* __restrict__ bq, const float* __restrict__ bk,
    const float* __restrict__ bv, const float* __restrict__ bo,
    const float* __restrict__ ln1g, const float* __restrict__ ln1b,
    const float* __restrict__ b1, const float* __restrict__ b2p,
    const float* __restrict__ ln2g, const float* __restrict__ ln2b,
    const float* __restrict__ Wf,
    const unsigned short* __restrict__ WswQ, const unsigned short* __restrict__ WswK,
    const unsigned short* __restrict__ WswV, const unsigned short* __restrict__ WswO,
    const unsigned short* __restrict__ Wsw1, const unsigned short* __restrict__ Wsw2,
    const float* __restrict__ PEt,
    float* __restrict__ acc1)
{
    __shared__ unsigned short ACT[128][STRD];  // activations / LN2 output
    __shared__ unsigned short Qb[128][STRD];   // Q -> ctx -> FF1 chunk
    __shared__ unsigned short Kb[128][STRD];   // K -> H (post-LN1)
    __shared__ unsigned short Vb[128][STRD];   // V
    __shared__ float LNp[128][4][2];           // per-row per-wave (sum, sumsq)
    __shared__ float LNs[128][2];              // per-row (mean, inv)

    const int t = threadIdx.x;
    const int w = t >> 6, lane = t & 63;
    const int q = lane >> 4, ln = lane & 15;
    const int bbase = blockIdx.x * G_B;

    // ---- load x + PE -> ACT (bf16) ----
    {
        const float4* xb = (const float4*)(x + (size_t)bbase * 2048);
        const float4* pe4 = (const float4*)PEt;
#pragma unroll
        for (int i = 0; i < 16; ++i) {
            int f4 = i * 256 + t;                  // 0..4095
            float4 xv = xb[f4];
            float4 pv = pe4[f4 & 511];
            int flat = f4 * 4;
            int row = flat >> 7, col = flat & 127;
            ushort4 pk = {f2b(xv.x + pv.x), f2b(xv.y + pv.y),
                          f2b(xv.z + pv.z), f2b(xv.w + pv.w)};
            *(ushort4*)&ACT[row][col] = pk;
        }
    }
    __syncthreads();

    for (int l = 0; l < 2; ++l) {
        // ================= QKV =================
        {
            bh8 afr[8][4];
#pragma unroll
            for (int mt = 0; mt < 8; ++mt)
#pragma unroll
                for (int ks = 0; ks < 4; ++ks)
                    afr[mt][ks] = *(const bh8*)&ACT[mt * 16 + ln][ks * 32 + q * 8];
            const unsigned short* Wm[3] = {WswQ + l * 16384, WswK + l * 16384, WswV + l * 16384};
            const float* bias3[3] = {bq + l * 128, bk + l * 128, bv + l * 128};
#pragma unroll
            for (int mtx = 0; mtx < 3; ++mtx) {
                unsigned short (*dst)[STRD] = (mtx == 0) ? Qb : (mtx == 1) ? Kb : Vb;
#pragma unroll
                for (int i2 = 0; i2 < 2; ++i2) {
                    int nt = w * 2 + i2;
                    bh8 wfr[4];
#pragma unroll
                    for (int ks = 0; ks < 4; ++ks)
                        wfr[ks] = *(const bh8*)(Wm[mtx] + ((nt * 4 + ks) * 64 + lane) * 8);
                    int n = nt * 16 + ln;
                    float bb = bias3[mtx][n];
#pragma unroll
                    for (int mt = 0; mt < 8; ++mt) {
                        fx4 acc = {0.f, 0.f, 0.f, 0.f};
#pragma unroll
                        for (int ks = 0; ks < 4; ++ks) acc = mfma16(afr[mt][ks], wfr[ks], acc);
#pragma unroll
                        for (int r2 = 0; r2 < 4; ++r2)
                            dst[mt * 16 + q * 4 + r2][n] = f2b(acc[r2] + bb);
                    }
                }
            }
        }
        __syncthreads();

        // ================= attention (verified raw-reshape, 2 b per wave) ====
#pragma unroll
        for (int bi = 0; bi < 2; ++bi) {
            int base = (w * 2 + bi) * 16;
            int g = lane >> 3, u0 = (lane & 7) * 2;
            float qr[2][16];
#pragma unroll
            for (int h = 0; h < 2; ++h) {
                int u = u0 + h;
                int qsr = base + 2 * g + (u >> 3), qc = (u & 7) * 16;
                bh8 a0 = *(const bh8*)&Qb[qsr][qc];
                bh8 a1 = *(const bh8*)&Qb[qsr][qc + 8];
#pragma unroll
                for (int e = 0; e < 8; ++e) {
                    qr[h][e] = bu2f((unsigned short)a0[e]);
                    qr[h][8 + e] = bu2f((unsigned short)a1[e]);
                }
            }
            float p[2][16];
#pragma unroll
            for (int tp = 0; tp < 16; ++tp) {
                int ksr = base + 2 * g + (tp >> 3), kc = (tp & 7) * 16;
                bh8 k0 = *(const bh8*)&Kb[ksr][kc];
                bh8 k1 = *(const bh8*)&Kb[ksr][kc + 8];
                float d0 = 0.f, d1 = 0.f;
#pragma unroll
                for (int e = 0; e < 8; ++e) {
                    float kv = bu2f((unsigned short)k0[e]);
                    d0 = fmaf(qr[0][e], kv, d0); d1 = fmaf(qr[1][e], kv, d1);
                }
#pragma unroll
                for (int e = 0; e < 8; ++e) {
                    float kv = bu2f((unsigned short)k1[e]);
                    d0 = fmaf(qr[0][8 + e], kv, d0); d1 = fmaf(qr[1][8 + e], kv, d1);
                }
                p[0][tp] = d0 * 0.25f; p[1][tp] = d1 * 0.25f;
            }
#pragma unroll
            for (int h = 0; h < 2; ++h) {
                float mx = -1e30f;
#pragma unroll
                for (int tp = 0; tp < 16; ++tp) mx = fmaxf(mx, p[h][tp]);
                float sum = 0.f;
#pragma unroll
                for (int tp = 0; tp < 16; ++tp) { p[h][tp] = __expf(p[h][tp] - mx); sum += p[h][tp]; }
                float is = 1.0f / sum;
#pragma unroll
                for (int tp = 0; tp < 16; ++tp) p[h][tp] *= is;
            }
            float ctx[2][16];
#pragma unroll
            for (int h = 0; h < 2; ++h)
#pragma unroll
                for (int e = 0; e < 16; ++e) ctx[h][e] = 0.f;
#pragma unroll
            for (int tp = 0; tp < 16; ++tp) {
                int vsr = base + 2 * g + (tp >> 3), vc = (tp & 7) * 16;
                bh8 v0 = *(const bh8*)&Vb[vsr][vc];
                bh8 v1 = *(const bh8*)&Vb[vsr][vc + 8];
#pragma unroll
                for (int e = 0; e < 8; ++e) {
                    float vv = bu2f((unsigned short)v0[e]);
                    ctx[0][e] = fmaf(p[0][tp], vv, ctx[0][e]);
                    ctx[1][e] = fmaf(p[1][tp], vv, ctx[1][e]);
                }
#pragma unroll
                for (int e = 0; e < 8; ++e) {
                    float vv = bu2f((unsigned short)v1[e]);
                    ctx[0][8 + e] = fmaf(p[0][tp], vv, ctx[0][8 + e]);
                    ctx[1][8 + e] = fmaf(p[1][tp], vv, ctx[1][8 + e]);
                }
            }
#pragma unroll
            for (int h = 0; h < 2; ++h) {
                int u = u0 + h;
                int s = base + 2 * g + (u >> 3), dc = (u & 7) * 16;
                bh8 c0, c1;
#pragma unroll
                for (int e = 0; e < 8; ++e) {
                    c0[e] = (short)f2b(ctx[h][e]);
                    c1[e] = (short)f2b(ctx[h][8 + e]);
                }
                *(bh8*)&Qb[s][dc] = c0;
                *(bh8*)&Qb[s][dc + 8] = c1;
            }
        }
        __syncthreads();

        // ================= O-proj + residual + LN1 -> Kb (H) ================
        fx4 Cv[2][8];
        {
            bh8 cfr[8][4];
#pragma unroll
            for (int mt = 0; mt < 8; ++mt)
#pragma unroll
                for (int ks = 0; ks < 4; ++ks)
                    cfr[mt][ks] = *(const bh8*)&Qb[mt * 16 + ln][ks * 32 + q * 8];
#pragma unroll
            for (int i2 = 0; i2 < 2; ++i2) {
                int nt = w * 2 + i2, n = nt * 16 + ln;
                bh8 wfr[4];
#pragma unroll
                for (int ks = 0; ks < 4; ++ks)
                    wfr[ks] = *(const bh8*)(WswO + l * 16384 + ((nt * 4 + ks) * 64 + lane) * 8);
                float bb = bo[l * 128 + n];
#pragma unroll
                for (int mt = 0; mt < 8; ++mt) {
                    fx4 acc = {0.f, 0.f, 0.f, 0.f};
#pragma unroll
                    for (int ks = 0; ks < 4; ++ks) acc = mfma16(cfr[mt][ks], wfr[ks], acc);
#pragma unroll
                    for (int r2 = 0; r2 < 4; ++r2)
                        Cv[i2][mt][r2] = acc[r2] + bb +
                            bu2f(ACT[mt * 16 + q * 4 + r2][n]);
                }
            }
        }
        // LN1 partials
#pragma unroll
        for (int mt = 0; mt < 8; ++mt) {
            float s4[4], v4[4];
#pragma unroll
            for (int r2 = 0; r2 < 4; ++r2) {
                float a0 = Cv[0][mt][r2], a1 = Cv[1][mt][r2];
                float s = a0 + a1, v = a0 * a0 + a1 * a1;
#pragma unroll
                for (int m = 1; m < 16; m <<= 1) { s += __shfl_xor(s, m); v += __shfl_xor(v, m); }
                s4[r2] = s; v4[r2] = v;
            }
            if (ln < 8)
                LNp[mt * 16 + q * 4 + (ln >> 1)][w][ln & 1] = (ln & 1) ? v4[ln >> 1] : s4[ln >> 1];
        }
        __syncthreads();
        if (t < 128) {
            float s = LNp[t][0][0] + LNp[t][1][0] + LNp[t][2][0] + LNp[t][3][0];
            float v = LNp[t][0][1] + LNp[t][1][1] + LNp[t][2][1] + LNp[t][3][1];
            float mean = s * (1.0f / 128.0f);
            LNs[t][0] = mean;
            LNs[t][1] = rsqrtf(v * (1.0f / 128.0f) - mean * mean + 1e-5f);
        }
        __syncthreads();
#pragma unroll
        for (int i2 = 0; i2 < 2; ++i2) {
            int n = (w * 2 + i2) * 16 + ln;
            float gg = ln1g[l * 128 + n], be = ln1b[l * 128 + n];
#pragma unroll
            for (int mt = 0; mt < 8; ++mt)
#pragma unroll
                for (int r2 = 0; r2 < 4; ++r2) {
                    int row = mt * 16 + q * 4 + r2;
                    Kb[row][n] = f2b((Cv[i2][mt][r2] - LNs[row][0]) * LNs[row][1] * gg + be);
                }
        }
        __syncthreads();

        // ================= FF (8 chunks of 128 hidden) ======================
        fx4 f2a[2][8];
#pragma unroll
        for (int i2 = 0; i2 < 2; ++i2)
#pragma unroll
            for (int mt = 0; mt < 8; ++mt) f2a[i2][mt] = fx4{0.f, 0.f, 0.f, 0.f};
        for (int ch = 0; ch < 8; ++ch) {
            bh8 w1fr[2][4];
#pragma unroll
            for (int i2 = 0; i2 < 2; ++i2) {
                int ntg = ch * 8 + w * 2 + i2;
#pragma unroll
                for (int ks = 0; ks < 4; ++ks)
                    w1fr[i2][ks] = *(const bh8*)(Wsw1 + l * 131072 + ((ntg * 4 + ks) * 64 + lane) * 8);
            }
#pragma unroll
            for (int mt = 0; mt < 8; ++mt) {
                bh8 hfr[4];
#pragma unroll
                for (int ks = 0; ks < 4; ++ks)
                    hfr[ks] = *(const bh8*)&Kb[mt * 16 + ln][ks * 32 + q * 8];
#pragma unroll
                for (int i2 = 0; i2 < 2; ++i2) {
                    fx4 acc = {0.f, 0.f, 0.f, 0.f};
#pragma unroll
                    for (int ks = 0; ks < 4; ++ks) acc = mfma16(hfr[ks], w1fr[i2][ks], acc);
                    int nl = (w * 2 + i2) * 16 + ln;
                    float bb = b1[l * HID_SZ + ch * 128 + nl];
#pragma unroll
                    for (int r2 = 0; r2 < 4; ++r2) {
                        float vv = acc[r2] + bb;
                        Qb[mt * 16 + q * 4 + r2][nl] = f2b(vv > 0.f ? vv : 0.f);
                    }
                }
            }
            __syncthreads();
            bh8 w2fr[2][4];
#pragma unroll
            for (int i2 = 0; i2 < 2; ++i2)
#pragma unroll
                for (int ks = 0; ks < 4; ++ks)
                    w2fr[i2][ks] = *(const bh8*)(Wsw2 + l * 131072 +
                        (((w * 2 + i2) * 32 + ch * 4 + ks) * 64 + lane) * 8);
#pragma unroll
            for (int mt = 0; mt < 8; ++mt) {
                bh8 ffr[4];
#pragma unroll
                for (int ks = 0; ks < 4; ++ks)
                    ffr[ks] = *(const bh8*)&Qb[mt * 16 + ln][ks * 32 + q * 8];
#pragma unroll
                for (int i2 = 0; i2 < 2; ++i2)
#pragma unroll
                    for (int ks = 0; ks < 4; ++ks)
                        f2a[i2][mt] = mfma16(ffr[ks], w2fr[i2][ks], f2a[i2][mt]);
            }
            __syncthreads();
        }
        // epilogue: + b2 + H residual, LN2 -> ACT
        fx4 Cv2[2][8];
#pragma unroll
        for (int i2 = 0; i2 < 2; ++i2) {
            int n = (w * 2 + i2) * 16 + ln;
            float bb = b2p[l * 128 + n];
#pragma unroll
            for (int mt = 0; mt < 8; ++mt)
#pragma unroll
                for (int r2 = 0; r2 < 4; ++r2)
                    Cv2[i2][mt][r2] = f2a[i2][mt][r2] + bb +
                        bu2f(Kb[mt * 16 + q * 4 + r2][n]);
        }
#pragma unroll
        for (int mt = 0; mt < 8; ++mt) {
            float s4[4], v4[4];
#pragma unroll
            for (int r2 = 0; r2 < 4; ++r2) {
                float a0 = Cv2[0][mt][r2], a1 = Cv2[1][mt][r2];
                float s = a0 + a1, v = a0 * a0 + a1 * a1;
#pragma unroll
                for (int m = 1; m < 16; m <<= 1) { s += __shfl_xor(s, m); v += __shfl_xor(v, m); }
                s4[r2] = s; v4[r2] = v;
            }
            if (ln < 8)
                LNp[mt * 16 + q * 4 + (ln >> 1)][w][ln & 1] = (ln & 1) ? v4[ln >> 1] : s4[ln >> 1];
        }
        __syncthreads();
        if (t < 128) {
            float s = LNp[t][0][0] + LNp[t][1][0] + LNp[t][2][0] + LNp[t][3][0];
            float v = LNp[t][0][1] + LNp[t][1][1] + LNp[t][2][1] + LNp[t][3][1];
            float mean = s * (1.0f / 128.0f);
            LNs[t][0] = mean;
            LNs[t][1] = rsqrtf(v * (1.0f / 128.0f) - mean * mean + 1e-5f);
        }
        __syncthreads();
#pragma unroll
        for (int i2 = 0; i2 < 2; ++i2) {
            int n = (w * 2 + i2) * 16 + ln;
            float gg = ln2g[l * 128 + n], be = ln2b[l * 128 + n];
#pragma unroll
            for (int mt = 0; mt < 8; ++mt)
#pragma unroll
                for (int r2 = 0; r2 < 4; ++r2) {
                    int row = mt * 16 + q * 4 + r2;
                    ACT[row][n] = f2b((Cv2[i2][mt][r2] - LNs[row][0]) * LNs[row][1] * gg + be);
                }
        }
        __syncthreads();
    }

    // ================= head partial dot ====================================
#pragma unroll
    for (int bi = 0; bi < 2; ++bi) {
        int bl = w * 2 + bi;
        int bg = bbase + bl;
        float part = 0.f;
        int srow = lane >> 2, c0 = (lane & 3) * 32;
#pragma unroll
        for (int i = 0; i < 4; ++i) {
            bh8 av = *(const bh8*)&ACT[bl * 16 + srow][c0 + i * 8];
            int fl = srow * 128 + c0 + i * 8;
#pragma unroll
            for (int e = 0; e < 8; ++e)
                part = fmaf(bu2f((unsigned short)av[e]), Wf[fl + e], part);
        }
        if (lane < GCN_SZ)
            part = fmaf(gcn[(size_t)bg * GCN_SZ + lane], Wf[2048 + lane], part);
#pragma unroll
        for (int off = 32; off; off >>= 1) part += __shfl_xor(part, off);
        if (lane == 0) acc1[bg] = part;
    }
}

// BN batch statistics: per-column sum / sumsq of n = num @ Wn + bnum.
__global__ __launch_bounds__(256) void num_stats_kernel(
    const float* __restrict__ num, const float* __restrict__ Wn,
    const float* __restrict__ bnum,
    float* __restrict__ ssum, float* __restrict__ ssq)
{
    __shared__ float NUM[16][NUMF_SZ + 1];
    __shared__ float cred[4][128];
    const int t = threadIdx.x;
    const int b0 = blockIdx.x * 16;
    const int j = t & 127, sg = t >> 7, s0 = sg * 8;

    for (int idx = t; idx < 16 * NUMF_SZ; idx += 256) {
        int r = idx / NUMF_SZ, f = idx - r * NUMF_SZ;
        NUM[r][f] = num[(size_t)(b0 + r) * NUMF_SZ + f];
    }
    __syncthreads();

    float acc[8];
    float bnv = bnum[j];
#pragma unroll
    for (int r = 0; r < 8; ++r) acc[r] = bnv;
    for (int f = 0; f < NUMF_SZ; ++f) {
        float w = Wn[f * 128 + j];
#pragma unroll
        for (int r = 0; r < 8; ++r) acc[r] = fmaf(NUM[s0 + r][f], w, acc[r]);
    }
    float lsum = 0.f, lsq = 0.f;
#pragma unroll
    for (int r = 0; r < 8; ++r) {
        lsum += acc[r];
        lsq = fmaf(acc[r], acc[r], lsq);
    }
    cred[sg][j] = lsum;
    cred[2 + sg][j] = lsq;
    __syncthreads();
    if (sg == 0) atomicAdd(&ssum[j], cred[0][j] + cred[1][j]);
    else         atomicAdd(&ssq[j],  cred[2][j] + cred[3][j]);
}

// Recompute n[b], BN(train-mode, biased var), final dot + sigmoid.
__global__ __launch_bounds__(128) void final_kernel(
    const float* __restrict__ num, const float* __restrict__ Wn,
    const float* __restrict__ bnum,
    const float* __restrict__ ssum, const float* __restrict__ ssq,
    const float* __restrict__ gamma, const float* __restrict__ beta,
    const float* __restrict__ Wf, const float* __restrict__ bfin,
    const float* __restrict__ acc1, float* __restrict__ out)
{
    const int b = blockIdx.x, jj = threadIdx.x;
    __shared__ float red2[2];
    __shared__ float NUMr[NUMF_SZ];
    if (jj < NUMF_SZ) NUMr[jj] = num[(size_t)b * NUMF_SZ + jj];
    __syncthreads();

    float nv = bnum[jj];
    for (int f = 0; f < NUMF_SZ; ++f)
        nv = fmaf(NUMr[f], Wn[f * 128 + jj], nv);

    float mean = ssum[jj] * (1.0f / (float)B_SZ);
    float var = ssq[jj] * (1.0f / (float)B_SZ) - mean * mean;
    float bnv = (nv - mean) * rsqrtf(var + 1e-5f) * gamma[jj] + beta[jj];
    float v = bnv * Wf[2088 + jj];
#pragma unroll
    for (int o = 32; o; o >>= 1) v += __shfl_down(v, o);
    if ((jj & 63) == 0) red2[jj >> 6] = v;
    __syncthreads();
    if (jj == 0) {
        float z = acc1[b] + red2[0] + red2[1] + bfin[0];
        out[b] = 1.0f / (1.0f + __expf(-z));
    }
}

extern "C" void kernel_launch(void* const* d_in, const int* in_sizes, int n_in,
                              void* d_out, int out_size, void* d_ws, size_t ws_size,
                              hipStream_t stream)
{
    const float* x    = (const float*)d_in[0];
    const float* gcn  = (const float*)d_in[1];
    const float* num  = (const float*)d_in[2];
    const float* Wq   = (const float*)d_in[3];
    const float* bq   = (const float*)d_in[4];
    const float* Wk   = (const float*)d_in[5];
    const float* bk   = (const float*)d_in[6];
    const float* Wv   = (const float*)d_in[7];
    const float* bv   = (const float*)d_in[8];
    const float* Wo   = (const float*)d_in[9];
    const float* bo   = (const float*)d_in[10];
    const float* ln1g = (const float*)d_in[11];
    const float* ln1b = (const float*)d_in[12];
    const float* W1   = (const float*)d_in[13];
    const float* b1   = (const float*)d_in[14];
    const float* W2   = (const float*)d_in[15];
    const float* b2p  = (const float*)d_in[16];
    const float* ln2g = (const float*)d_in[17];
    const float* ln2b = (const float*)d_in[18];
    const float* Wn   = (const float*)d_in[19];
    const float* bnum = (const float*)d_in[20];
    const float* bng  = (const float*)d_in[21];
    const float* bnb  = (const float*)d_in[22];
    const float* Wf   = (const float*)d_in[23];
    const float* bfin = (const float*)d_in[24];

    // ws: acc1 (8192 f32) | ssum | ssq | pad to 40960 B | swizzled bf16 weights | PE
    float* acc1 = (float*)d_ws;
    float* ssum = acc1 + B_SZ;
    float* ssq  = ssum + 128;
    unsigned short* wb = (unsigned short*)((char*)d_ws + 40960);
    unsigned short* WswQ = wb;
    unsigned short* WswK = wb + 32768;
    unsigned short* WswV = wb + 65536;
    unsigned short* WswO = wb + 98304;
    unsigned short* Wsw1 = wb + 131072;
    unsigned short* Wsw2 = wb + 393216;
    float* PEt = (float*)((char*)d_ws + 40960 + 1310720);

    hipMemsetAsync(ssum, 0, 2 * 128 * sizeof(float), stream);
    prep_weights<<<1024, 256, 0, stream>>>(Wq, Wk, Wv, Wo, W1, W2,
        WswQ, WswK, WswV, WswO, Wsw1, Wsw2, PEt);
    encoder_fused<<<NBLK, 256, 0, stream>>>(x, gcn, bq, bk, bv, bo,
        ln1g, ln1b, b1, b2p, ln2g, ln2b, Wf,
        WswQ, WswK, WswV, WswO, Wsw1, Wsw2, PEt, acc1);
    num_stats_kernel<<<B_SZ / 16, 256, 0, stream>>>(num, Wn, bnum, ssum, ssq);
    final_kernel<<<B_SZ, 128, 0, stream>>>(num, Wn, bnum, ssum, ssq, bng, bnb,
        Wf, bfin, acc1, (float*)d_out);
}

// Round 7
// 491.106 us; speedup vs baseline: 30.5667x; 1.3091x over previous
//
#include <hip/hip_runtime.h>
#include <hip/hip_bf16.h>
#include <math.h>

#define B_SZ   8192
#define S_SZ   16
#define D_SZ   128
#define HID_SZ 1024
#define NUMF_SZ 103
#define GCN_SZ 40
#define G_B    4                 // batch elements per block (64 rows)
#define NBLK   (B_SZ / G_B)      // 2048 blocks
#define STRD   136               // LDS row stride (shorts), pad 8

typedef short bh8 __attribute__((ext_vector_type(8)));   // 8 bf16 (4 VGPRs)
typedef float fx4 __attribute__((ext_vector_type(4)));   // MFMA accumulator

__device__ __forceinline__ fx4 mfma16(bh8 a, bh8 b, fx4 c) {
    return __builtin_amdgcn_mfma_f32_16x16x32_bf16(a, b, c, 0, 0, 0);
}

// fp32 -> bf16 bits, round-nearest-even
__device__ __forceinline__ unsigned short f2b(float f) {
    unsigned u = __float_as_uint(f);
    return (unsigned short)((u + 0x7fffu + ((u >> 16) & 1u)) >> 16);
}
__device__ __forceinline__ float bu2f(unsigned short u) {
    return __uint_as_float(((unsigned)u) << 16);
}

// Swizzle all weights into B-fragment-linear bf16 order:
//   QKVO : [l][nt(8)][ks(4)][lane(64)][e(8)]   (nt = n/16, k = ks*32 + q*8 + e)
//   W1   : [l][nt(64)][ks(4)][lane][e]
//   W2   : [l][nt(8)][kt(32)][lane][e]
// so a wave's fragment load is one contiguous 1KB block (lane*16B).
__global__ __launch_bounds__(256) void prep_weights(
    const float* __restrict__ Wq, const float* __restrict__ Wk,
    const float* __restrict__ Wv, const float* __restrict__ Wo,
    const float* __restrict__ W1, const float* __restrict__ W2,
    unsigned short* __restrict__ WswQ, unsigned short* __restrict__ WswK,
    unsigned short* __restrict__ WswV, unsigned short* __restrict__ WswO,
    unsigned short* __restrict__ Wsw1, unsigned short* __restrict__ Wsw2,
    float* __restrict__ PEt)
{
    int i = blockIdx.x * 256 + threadIdx.x;
    if (i < 2048) {  // PE table [16][128]
        int s = i >> 7, c = i & 127;
        float expo = (float)((c >> 1) * 2) * (1.0f / 128.0f);
        float denom = powf(10000.0f, expo);
        float ang = (float)s / denom;
        PEt[i] = (c & 1) ? cosf(ang) : sinf(ang);
    }
    if (i < 2 * 16384) {   // QKVO, dst-driven
        int l = i >> 14, r = i & 16383;
        int nt = r >> 11, ks = (r >> 9) & 3, lane = (r >> 3) & 63, e = r & 7;
        int k = ks * 32 + (lane >> 4) * 8 + e;
        int n = nt * 16 + (lane & 15);
        int s = l * 16384 + k * 128 + n;
        WswQ[i] = f2b(Wq[s]); WswK[i] = f2b(Wk[s]);
        WswV[i] = f2b(Wv[s]); WswO[i] = f2b(Wo[s]);
    }
    {   // W1: src [l][k=128][n=1024]
        int l = i >> 17, r = i & 131071;
        int nt = r >> 11, ks = (r >> 9) & 3, lane = (r >> 3) & 63, e = r & 7;
        int k = ks * 32 + (lane >> 4) * 8 + e;
        int n = nt * 16 + (lane & 15);
        Wsw1[i] = f2b(W1[l * 131072 + k * 1024 + n]);
    }
    {   // W2: src [l][k=1024][n=128]
        int l = i >> 17, r = i & 131071;
        int nt = r >> 14, kt = (r >> 9) & 31, lane = (r >> 3) & 63, e = r & 7;
        int k = kt * 32 + (lane >> 4) * 8 + e;
        int n = nt * 16 + (lane & 15);
        Wsw2[i] = f2b(W2[l * 131072 + k * 128 + n]);
    }
}

// Block = 4 waves = 4 batch elements (64 rows). Waves split N (2 n-tiles each).
// LDS ~72 KB -> 2 independent blocks/CU (2 waves/SIMD) for latency hiding.
__global__ __launch_bounds__(256, 2) void encoder_fused(
    const float* __restrict__ x, const float* __restrict__ gcn,
    const float* __restrict__ bq, const float* __restrict__ bk,
    const float* __restrict__ bv, const float* __restrict__ bo,
    const float* __restrict__ ln1g, const float* __restrict__ ln1b,
    const float* __restrict__ b1, const float* __restrict__ b2p,
    const float* __restrict__ ln2g, const float* __restrict__ ln2b,
    const float* __restrict__ Wf,
    const unsigned short* __restrict__ WswQ, const unsigned short* __restrict__ WswK,
    const unsigned short* __restrict__ WswV, const unsigned short* __restrict__ WswO,
    const unsigned short* __restrict__ Wsw1, const unsigned short* __restrict__ Wsw2,
    const float* __restrict__ PEt,
    float* __restrict__ acc1)
{
    __shared__ unsigned short ACT[64][STRD];  // activations / LN2 output
    __shared__ unsigned short Qb[64][STRD];   // Q -> ctx -> FF1 chunk
    __shared__ unsigned short Kb[64][STRD];   // K -> H (post-LN1)
    __shared__ unsigned short Vb[64][STRD];   // V
    __shared__ float LNp[64][4][2];           // per-row per-wave (sum, sumsq)
    __shared__ float LNs[64][2];              // per-row (mean, inv)

    const int t = threadIdx.x;
    const int w = t >> 6, lane = t & 63;
    const int q = lane >> 4, ln = lane & 15;
    const int bbase = blockIdx.x * G_B;

    // ---- load x + PE -> ACT (bf16) ----
    {
        const float4* xb = (const float4*)(x + (size_t)bbase * 2048);
        const float4* pe4 = (const float4*)PEt;
#pragma unroll
        for (int i = 0; i < 8; ++i) {
            int f4 = i * 256 + t;                  // 0..2047
            float4 xv = xb[f4];
            float4 pv = pe4[f4 & 511];
            int flat = f4 * 4;
            int row = flat >> 7, col = flat & 127;
            ushort4 pk = {f2b(xv.x + pv.x), f2b(xv.y + pv.y),
                          f2b(xv.z + pv.z), f2b(xv.w + pv.w)};
            *(ushort4*)&ACT[row][col] = pk;
        }
    }
    __syncthreads();

    for (int l = 0; l < 2; ++l) {
        // ================= QKV =================
        {
            bh8 afr[4][4];
#pragma unroll
            for (int mt = 0; mt < 4; ++mt)
#pragma unroll
                for (int ks = 0; ks < 4; ++ks)
                    afr[mt][ks] = *(const bh8*)&ACT[mt * 16 + ln][ks * 32 + q * 8];
            const unsigned short* Wm[3] = {WswQ + l * 16384, WswK + l * 16384, WswV + l * 16384};
            const float* bias3[3] = {bq + l * 128, bk + l * 128, bv + l * 128};
#pragma unroll
            for (int mtx = 0; mtx < 3; ++mtx) {
                unsigned short (*dst)[STRD] = (mtx == 0) ? Qb : (mtx == 1) ? Kb : Vb;
#pragma unroll
                for (int i2 = 0; i2 < 2; ++i2) {
                    int nt = w * 2 + i2;
                    bh8 wfr[4];
#pragma unroll
                    for (int ks = 0; ks < 4; ++ks)
                        wfr[ks] = *(const bh8*)(Wm[mtx] + ((nt * 4 + ks) * 64 + lane) * 8);
                    int n = nt * 16 + ln;
                    float bb = bias3[mtx][n];
#pragma unroll
                    for (int mt = 0; mt < 4; ++mt) {
                        fx4 acc = {0.f, 0.f, 0.f, 0.f};
#pragma unroll
                        for (int ks = 0; ks < 4; ++ks) acc = mfma16(afr[mt][ks], wfr[ks], acc);
#pragma unroll
                        for (int r2 = 0; r2 < 4; ++r2)
                            dst[mt * 16 + q * 4 + r2][n] = f2b(acc[r2] + bb);
                    }
                }
            }
        }
        __syncthreads();

        // ===== attention (verified raw-reshape): wave w owns batch row-tile w
        {
            int base = w * 16;
            int g = lane >> 3, u0 = (lane & 7) * 2;
            float qr[2][16];
#pragma unroll
            for (int h = 0; h < 2; ++h) {
                int u = u0 + h;
                int qsr = base + 2 * g + (u >> 3), qc = (u & 7) * 16;
                bh8 a0 = *(const bh8*)&Qb[qsr][qc];
                bh8 a1 = *(const bh8*)&Qb[qsr][qc + 8];
#pragma unroll
                for (int e = 0; e < 8; ++e) {
                    qr[h][e] = bu2f((unsigned short)a0[e]);
                    qr[h][8 + e] = bu2f((unsigned short)a1[e]);
                }
            }
            float p[2][16];
#pragma unroll
            for (int tp = 0; tp < 16; ++tp) {
                int ksr = base + 2 * g + (tp >> 3), kc = (tp & 7) * 16;
                bh8 k0 = *(const bh8*)&Kb[ksr][kc];
                bh8 k1 = *(const bh8*)&Kb[ksr][kc + 8];
                float d0 = 0.f, d1 = 0.f;
#pragma unroll
                for (int e = 0; e < 8; ++e) {
                    float kv = bu2f((unsigned short)k0[e]);
                    d0 = fmaf(qr[0][e], kv, d0); d1 = fmaf(qr[1][e], kv, d1);
                }
#pragma unroll
                for (int e = 0; e < 8; ++e) {
                    float kv = bu2f((unsigned short)k1[e]);
                    d0 = fmaf(qr[0][8 + e], kv, d0); d1 = fmaf(qr[1][8 + e], kv, d1);
                }
                p[0][tp] = d0 * 0.25f; p[1][tp] = d1 * 0.25f;
            }
#pragma unroll
            for (int h = 0; h < 2; ++h) {
                float mx = -1e30f;
#pragma unroll
                for (int tp = 0; tp < 16; ++tp) mx = fmaxf(mx, p[h][tp]);
                float sum = 0.f;
#pragma unroll
                for (int tp = 0; tp < 16; ++tp) { p[h][tp] = __expf(p[h][tp] - mx); sum += p[h][tp]; }
                float is = 1.0f / sum;
#pragma unroll
                for (int tp = 0; tp < 16; ++tp) p[h][tp] *= is;
            }
            float ctx[2][16];
#pragma unroll
            for (int h = 0; h < 2; ++h)
#pragma unroll
                for (int e = 0; e < 16; ++e) ctx[h][e] = 0.f;
#pragma unroll
            for (int tp = 0; tp < 16; ++tp) {
                int vsr = base + 2 * g + (tp >> 3), vc = (tp & 7) * 16;
                bh8 v0 = *(const bh8*)&Vb[vsr][vc];
                bh8 v1 = *(const bh8*)&Vb[vsr][vc + 8];
#pragma unroll
                for (int e = 0; e < 8; ++e) {
                    float vv = bu2f((unsigned short)v0[e]);
                    ctx[0][e] = fmaf(p[0][tp], vv, ctx[0][e]);
                    ctx[1][e] = fmaf(p[1][tp], vv, ctx[1][e]);
                }
#pragma unroll
                for (int e = 0; e < 8; ++e) {
                    float vv = bu2f((unsigned short)v1[e]);
                    ctx[0][8 + e] = fmaf(p[0][tp], vv, ctx[0][8 + e]);
                    ctx[1][8 + e] = fmaf(p[1][tp], vv, ctx[1][8 + e]);
                }
            }
#pragma unroll
            for (int h = 0; h < 2; ++h) {
                int u = u0 + h;
                int s = base + 2 * g + (u >> 3), dc = (u & 7) * 16;
                bh8 c0, c1;
#pragma unroll
                for (int e = 0; e < 8; ++e) {
                    c0[e] = (short)f2b(ctx[h][e]);
                    c1[e] = (short)f2b(ctx[h][8 + e]);
                }
                *(bh8*)&Qb[s][dc] = c0;
                *(bh8*)&Qb[s][dc + 8] = c1;
            }
        }
        __syncthreads();

        // ================= O-proj + residual + LN1 -> Kb (H) ================
        fx4 Cv[2][4];
        {
            bh8 cfr[4][4];
#pragma unroll
            for (int mt = 0; mt < 4; ++mt)
#pragma unroll
                for (int ks = 0; ks < 4; ++ks)
                    cfr[mt][ks] = *(const bh8*)&Qb[mt * 16 + ln][ks * 32 + q * 8];
#pragma unroll
            for (int i2 = 0; i2 < 2; ++i2) {
                int nt = w * 2 + i2, n = nt * 16 + ln;
                bh8 wfr[4];
#pragma unroll
                for (int ks = 0; ks < 4; ++ks)
                    wfr[ks] = *(const bh8*)(WswO + l * 16384 + ((nt * 4 + ks) * 64 + lane) * 8);
                float bb = bo[l * 128 + n];
#pragma unroll
                for (int mt = 0; mt < 4; ++mt) {
                    fx4 acc = {0.f, 0.f, 0.f, 0.f};
#pragma unroll
                    for (int ks = 0; ks < 4; ++ks) acc = mfma16(cfr[mt][ks], wfr[ks], acc);
#pragma unroll
                    for (int r2 = 0; r2 < 4; ++r2)
                        Cv[i2][mt][r2] = acc[r2] + bb +
                            bu2f(ACT[mt * 16 + q * 4 + r2][n]);
                }
            }
        }
        // LN1 partials
#pragma unroll
        for (int mt = 0; mt < 4; ++mt) {
            float s4[4], v4[4];
#pragma unroll
            for (int r2 = 0; r2 < 4; ++r2) {
                float a0 = Cv[0][mt][r2], a1 = Cv[1][mt][r2];
                float s = a0 + a1, v = a0 * a0 + a1 * a1;
#pragma unroll
                for (int m = 1; m < 16; m <<= 1) { s += __shfl_xor(s, m); v += __shfl_xor(v, m); }
                s4[r2] = s; v4[r2] = v;
            }
            if (ln < 8)
                LNp[mt * 16 + q * 4 + (ln >> 1)][w][ln & 1] = (ln & 1) ? v4[ln >> 1] : s4[ln >> 1];
        }
        __syncthreads();
        if (t < 64) {
            float s = LNp[t][0][0] + LNp[t][1][0] + LNp[t][2][0] + LNp[t][3][0];
            float v = LNp[t][0][1] + LNp[t][1][1] + LNp[t][2][1] + LNp[t][3][1];
            float mean = s * (1.0f / 128.0f);
            LNs[t][0] = mean;
            LNs[t][1] = rsqrtf(v * (1.0f / 128.0f) - mean * mean + 1e-5f);
        }
        __syncthreads();
#pragma unroll
        for (int i2 = 0; i2 < 2; ++i2) {
            int n = (w * 2 + i2) * 16 + ln;
            float gg = ln1g[l * 128 + n], be = ln1b[l * 128 + n];
#pragma unroll
            for (int mt = 0; mt < 4; ++mt)
#pragma unroll
                for (int r2 = 0; r2 < 4; ++r2) {
                    int row = mt * 16 + q * 4 + r2;
                    Kb[row][n] = f2b((Cv[i2][mt][r2] - LNs[row][0]) * LNs[row][1] * gg + be);
                }
        }
        __syncthreads();

        // ================= FF (8 chunks of 128 hidden) ======================
        // H fragments are loop-invariant across chunks: hoist (big LDS saving)
        bh8 hfr[4][4];
#pragma unroll
        for (int mt = 0; mt < 4; ++mt)
#pragma unroll
            for (int ks = 0; ks < 4; ++ks)
                hfr[mt][ks] = *(const bh8*)&Kb[mt * 16 + ln][ks * 32 + q * 8];
        fx4 f2a[2][4];
#pragma unroll
        for (int i2 = 0; i2 < 2; ++i2)
#pragma unroll
            for (int mt = 0; mt < 4; ++mt) f2a[i2][mt] = fx4{0.f, 0.f, 0.f, 0.f};
        for (int ch = 0; ch < 8; ++ch) {
            bh8 w1fr[2][4];
#pragma unroll
            for (int i2 = 0; i2 < 2; ++i2) {
                int ntg = ch * 8 + w * 2 + i2;
#pragma unroll
                for (int ks = 0; ks < 4; ++ks)
                    w1fr[i2][ks] = *(const bh8*)(Wsw1 + l * 131072 + ((ntg * 4 + ks) * 64 + lane) * 8);
            }
#pragma unroll
            for (int mt = 0; mt < 4; ++mt) {
#pragma unroll
                for (int i2 = 0; i2 < 2; ++i2) {
                    fx4 acc = {0.f, 0.f, 0.f, 0.f};
#pragma unroll
                    for (int ks = 0; ks < 4; ++ks) acc = mfma16(hfr[mt][ks], w1fr[i2][ks], acc);
                    int nl = (w * 2 + i2) * 16 + ln;
                    float bb = b1[l * HID_SZ + ch * 128 + nl];
#pragma unroll
                    for (int r2 = 0; r2 < 4; ++r2) {
                        float vv = acc[r2] + bb;
                        Qb[mt * 16 + q * 4 + r2][nl] = f2b(vv > 0.f ? vv : 0.f);
                    }
                }
            }
            __syncthreads();
            bh8 w2fr[2][4];
#pragma unroll
            for (int i2 = 0; i2 < 2; ++i2)
#pragma unroll
                for (int ks = 0; ks < 4; ++ks)
                    w2fr[i2][ks] = *(const bh8*)(Wsw2 + l * 131072 +
                        (((w * 2 + i2) * 32 + ch * 4 + ks) * 64 + lane) * 8);
#pragma unroll
            for (int mt = 0; mt < 4; ++mt) {
                bh8 ffr[4];
#pragma unroll
                for (int ks = 0; ks < 4; ++ks)
                    ffr[ks] = *(const bh8*)&Qb[mt * 16 + ln][ks * 32 + q * 8];
#pragma unroll
                for (int i2 = 0; i2 < 2; ++i2)
#pragma unroll
                    for (int ks = 0; ks < 4; ++ks)
                        f2a[i2][mt] = mfma16(ffr[ks], w2fr[i2][ks], f2a[i2][mt]);
            }
            __syncthreads();
        }
        // epilogue: + b2 + H residual, LN2 -> ACT
        fx4 Cv2[2][4];
#pragma unroll
        for (int i2 = 0; i2 < 2; ++i2) {
            int n = (w * 2 + i2) * 16 + ln;
            float bb = b2p[l * 128 + n];
#pragma unroll
            for (int mt = 0; mt < 4; ++mt)
#pragma unroll
                for (int r2 = 0; r2 < 4; ++r2)
                    Cv2[i2][mt][r2] = f2a[i2][mt][r2] + bb +
                        bu2f(Kb[mt * 16 + q * 4 + r2][n]);
        }
#pragma unroll
        for (int mt = 0; mt < 4; ++mt) {
            float s4[4], v4[4];
#pragma unroll
            for (int r2 = 0; r2 < 4; ++r2) {
                float a0 = Cv2[0][mt][r2], a1 = Cv2[1][mt][r2];
                float s = a0 + a1, v = a0 * a0 + a1 * a1;
#pragma unroll
                for (int m = 1; m < 16; m <<= 1) { s += __shfl_xor(s, m); v += __shfl_xor(v, m); }
                s4[r2] = s; v4[r2] = v;
            }
            if (ln < 8)
                LNp[mt * 16 + q * 4 + (ln >> 1)][w][ln & 1] = (ln & 1) ? v4[ln >> 1] : s4[ln >> 1];
        }
        __syncthreads();
        if (t < 64) {
            float s = LNp[t][0][0] + LNp[t][1][0] + LNp[t][2][0] + LNp[t][3][0];
            float v = LNp[t][0][1] + LNp[t][1][1] + LNp[t][2][1] + LNp[t][3][1];
            float mean = s * (1.0f / 128.0f);
            LNs[t][0] = mean;
            LNs[t][1] = rsqrtf(v * (1.0f / 128.0f) - mean * mean + 1e-5f);
        }
        __syncthreads();
#pragma unroll
        for (int i2 = 0; i2 < 2; ++i2) {
            int n = (w * 2 + i2) * 16 + ln;
            float gg = ln2g[l * 128 + n], be = ln2b[l * 128 + n];
#pragma unroll
            for (int mt = 0; mt < 4; ++mt)
#pragma unroll
                for (int r2 = 0; r2 < 4; ++r2) {
                    int row = mt * 16 + q * 4 + r2;
                    ACT[row][n] = f2b((Cv2[i2][mt][r2] - LNs[row][0]) * LNs[row][1] * gg + be);
                }
        }
        __syncthreads();
    }

    // ============ head partial dot: wave w handles batch bbase + w =========
    {
        int bg = bbase + w;
        float part = 0.f;
        int srow = lane >> 2, c0 = (lane & 3) * 32;
#pragma unroll
        for (int i = 0; i < 4; ++i) {
            bh8 av = *(const bh8*)&ACT[w * 16 + srow][c0 + i * 8];
            int fl = srow * 128 + c0 + i * 8;
#pragma unroll
            for (int e = 0; e < 8; ++e)
                part = fmaf(bu2f((unsigned short)av[e]), Wf[fl + e], part);
        }
        if (lane < GCN_SZ)
            part = fmaf(gcn[(size_t)bg * GCN_SZ + lane], Wf[2048 + lane], part);
#pragma unroll
        for (int off = 32; off; off >>= 1) part += __shfl_xor(part, off);
        if (lane == 0) acc1[bg] = part;
    }
}

// BN batch statistics: per-column sum / sumsq of n = num @ Wn + bnum.
__global__ __launch_bounds__(256) void num_stats_kernel(
    const float* __restrict__ num, const float* __restrict__ Wn,
    const float* __restrict__ bnum,
    float* __restrict__ ssum, float* __restrict__ ssq)
{
    __shared__ float NUM[16][NUMF_SZ + 1];
    __shared__ float cred[4][128];
    const int t = threadIdx.x;
    const int b0 = blockIdx.x * 16;
    const int j = t & 127, sg = t >> 7, s0 = sg * 8;

    for (int idx = t; idx < 16 * NUMF_SZ; idx += 256) {
        int r = idx / NUMF_SZ, f = idx - r * NUMF_SZ;
        NUM[r][f] = num[(size_t)(b0 + r) * NUMF_SZ + f];
    }
    __syncthreads();

    float acc[8];
    float bnv = bnum[j];
#pragma unroll
    for (int r = 0; r < 8; ++r) acc[r] = bnv;
    for (int f = 0; f < NUMF_SZ; ++f) {
        float w = Wn[f * 128 + j];
#pragma unroll
        for (int r = 0; r < 8; ++r) acc[r] = fmaf(NUM[s0 + r][f], w, acc[r]);
    }
    float lsum = 0.f, lsq = 0.f;
#pragma unroll
    for (int r = 0; r < 8; ++r) {
        lsum += acc[r];
        lsq = fmaf(acc[r], acc[r], lsq);
    }
    cred[sg][j] = lsum;
    cred[2 + sg][j] = lsq;
    __syncthreads();
    if (sg == 0) atomicAdd(&ssum[j], cred[0][j] + cred[1][j]);
    else         atomicAdd(&ssq[j],  cred[2][j] + cred[3][j]);
}

// Recompute n[b], BN(train-mode, biased var), final dot + sigmoid.
__global__ __launch_bounds__(128) void final_kernel(
    const float* __restrict__ num, const float* __restrict__ Wn,
    const float* __restrict__ bnum,
    const float* __restrict__ ssum, const float* __restrict__ ssq,
    const float* __restrict__ gamma, const float* __restrict__ beta,
    const float* __restrict__ Wf, const float* __restrict__ bfin,
    const float* __restrict__ acc1, float* __restrict__ out)
{
    const int b = blockIdx.x, jj = threadIdx.x;
    __shared__ float red2[2];
    __shared__ float NUMr[NUMF_SZ];
    if (jj < NUMF_SZ) NUMr[jj] = num[(size_t)b * NUMF_SZ + jj];
    __syncthreads();

    float nv = bnum[jj];
    for (int f = 0; f < NUMF_SZ; ++f)
        nv = fmaf(NUMr[f], Wn[f * 128 + jj], nv);

    float mean = ssum[jj] * (1.0f / (float)B_SZ);
    float var = ssq[jj] * (1.0f / (float)B_SZ) - mean * mean;
    float bnv = (nv - mean) * rsqrtf(var + 1e-5f) * gamma[jj] + beta[jj];
    float v = bnv * Wf[2088 + jj];
#pragma unroll
    for (int o = 32; o; o >>= 1) v += __shfl_down(v, o);
    if ((jj & 63) == 0) red2[jj >> 6] = v;
    __syncthreads();
    if (jj == 0) {
        float z = acc1[b] + red2[0] + red2[1] + bfin[0];
        out[b] = 1.0f / (1.0f + __expf(-z));
    }
}

extern "C" void kernel_launch(void* const* d_in, const int* in_sizes, int n_in,
                              void* d_out, int out_size, void* d_ws, size_t ws_size,
                              hipStream_t stream)
{
    const float* x    = (const float*)d_in[0];
    const float* gcn  = (const float*)d_in[1];
    const float* num  = (const float*)d_in[2];
    const float* Wq   = (const float*)d_in[3];
    const float* bq   = (const float*)d_in[4];
    const float* Wk   = (const float*)d_in[5];
    const float* bk   = (const float*)d_in[6];
    const float* Wv   = (const float*)d_in[7];
    const float* bv   = (const float*)d_in[8];
    const float* Wo   = (const float*)d_in[9];
    const float* bo   = (const float*)d_in[10];
    const float* ln1g = (const float*)d_in[11];
    const float* ln1b = (const float*)d_in[12];
    const float* W1   = (const float*)d_in[13];
    const float* b1   = (const float*)d_in[14];
    const float* W2   = (const float*)d_in[15];
    const float* b2p  = (const float*)d_in[16];
    const float* ln2g = (const float*)d_in[17];
    const float* ln2b = (const float*)d_in[18];
    const float* Wn   = (const float*)d_in[19];
    const float* bnum = (const float*)d_in[20];
    const float* bng  = (const float*)d_in[21];
    const float* bnb  = (const float*)d_in[22];
    const float* Wf   = (const float*)d_in[23];
    const float* bfin = (const float*)d_in[24];

    // ws: acc1 (8192 f32) | ssum | ssq | pad to 40960 B | swizzled bf16 weights | PE
    float* acc1 = (float*)d_ws;
    float* ssum = acc1 + B_SZ;
    float* ssq  = ssum + 128;
    unsigned short* wb = (unsigned short*)((char*)d_ws + 40960);
    unsigned short* WswQ = wb;
    unsigned short* WswK = wb + 32768;
    unsigned short* WswV = wb + 65536;
    unsigned short* WswO = wb + 98304;
    unsigned short* Wsw1 = wb + 131072;
    unsigned short* Wsw2 = wb + 393216;
    float* PEt = (float*)((char*)d_ws + 40960 + 1310720);

    hipMemsetAsync(ssum, 0, 2 * 128 * sizeof(float), stream);
    prep_weights<<<1024, 256, 0, stream>>>(Wq, Wk, Wv, Wo, W1, W2,
        WswQ, WswK, WswV, WswO, Wsw1, Wsw2, PEt);
    encoder_fused<<<NBLK, 256, 0, stream>>>(x, gcn, bq, bk, bv, bo,
        ln1g, ln1b, b1, b2p, ln2g, ln2b, Wf,
        WswQ, WswK, WswV, WswO, Wsw1, Wsw2, PEt, acc1);
    num_stats_kernel<<<B_SZ / 16, 256, 0, stream>>>(num, Wn, bnum, ssum, ssq);
    final_kernel<<<B_SZ, 128, 0, stream>>>(num, Wn, bnum, ssum, ssq, bng, bnb,
        Wf, bfin, acc1, (float*)d_out);
}